// Round 17
// baseline (183.059 us; speedup 1.0000x reference)
//
#include <hip/hip_runtime.h>

#define HID 768
#define NHEAD 12
#define HD 64
#define SEQ 2048
#define BATCH 2
#define PH (BATCH * NHEAD * SEQ * HD)   // 3,145,728 elements per Q/K/V plane
#define XEL (BATCH * SEQ * HID)
#define LOG2E 1.4426950408889634f
#define C1 (0.125f * LOG2E)             // QK scale folded with log2e
#define FMAX2 16.0f                     // fixed softmax max (log2 domain)

typedef __attribute__((ext_vector_type(8))) short bf16x8;
typedef __attribute__((ext_vector_type(4))) short bf16x4;
typedef __attribute__((ext_vector_type(4))) float f32x4;
typedef __attribute__((ext_vector_type(16))) float f32x16;

static __device__ __forceinline__ short f2b(float f) {
  unsigned int u = __builtin_bit_cast(unsigned int, f);
  unsigned int r = (u + 0x7fffu + ((u >> 16) & 1u)) >> 16;
  return (short)(unsigned short)r;
}

static __device__ __forceinline__ float fexp2(float x) {
  float r; asm("v_exp_f32 %0, %1" : "=v"(r) : "v"(x)); return r;
}

// ---------------------------------------------------------------------------
// Prep: X->bf16, W transpose->Wt[n][k] bf16, mask2 = mask*log2e - FMAX2
// ---------------------------------------------------------------------------
__global__ __launch_bounds__(256) void prep(
    const float* __restrict__ X,
    const float* __restrict__ Wq, const float* __restrict__ Wk,
    const float* __restrict__ Wv, const float* __restrict__ mask,
    short* __restrict__ Xb, short* __restrict__ Wt, float* __restrict__ mask2)
{
  __shared__ short T[64][65];
  const int t = threadIdx.x;
  const int blk = blockIdx.x;
  if (blk < 768) {
    const size_t base = (size_t)blk * 4096 + t * 16;
    f32x4 a0 = *(const f32x4*)(X + base);
    f32x4 a1 = *(const f32x4*)(X + base + 4);
    f32x4 a2 = *(const f32x4*)(X + base + 8);
    f32x4 a3 = *(const f32x4*)(X + base + 12);
    bf16x8 o0, o1;
#pragma unroll
    for (int i = 0; i < 4; ++i) {
      o0[i] = f2b(a0[i]); o0[4 + i] = f2b(a1[i]);
      o1[i] = f2b(a2[i]); o1[4 + i] = f2b(a3[i]);
    }
    *(bf16x8*)(Xb + base) = o0;
    *(bf16x8*)(Xb + base + 8) = o1;
  } else if (blk < 1200) {
    const int wb   = blk - 768;
    const int mat  = wb / 144;
    const int tile = wb - mat * 144;
    const int r0 = (tile / 12) * 64;
    const int c0 = (tile % 12) * 64;
    const float* __restrict__ W = (mat == 0) ? Wq : (mat == 1 ? Wk : Wv);
#pragma unroll
    for (int i = 0; i < 4; ++i) {
      const int r = (t >> 4) + 16 * i;
      const int c = (t & 15) * 4;
      f32x4 v = *(const f32x4*)(W + (size_t)(r0 + r) * HID + c0 + c);
      T[r][c + 0] = f2b(v[0]); T[r][c + 1] = f2b(v[1]);
      T[r][c + 2] = f2b(v[2]); T[r][c + 3] = f2b(v[3]);
    }
    __syncthreads();
    const int cr = t >> 2;
    const int ck = (t & 3) * 16;
    bf16x8 u0, u1;
#pragma unroll
    for (int j = 0; j < 8; ++j) { u0[j] = T[ck + j][cr]; u1[j] = T[ck + 8 + j][cr]; }
    short* orow = Wt + (size_t)(mat * HID + c0 + cr) * HID + r0 + ck;
    *(bf16x8*)orow = u0;
    *(bf16x8*)(orow + 8) = u1;
  } else {
#pragma unroll
    for (int i = 0; i < 4; ++i) {
      const int idx = (t * 4 + i * 1024);
      f32x4 v = *(const f32x4*)(mask + idx);
      v = v * LOG2E - FMAX2;
      *(f32x4*)(mask2 + idx) = v;
    }
  }
}

// ---------------------------------------------------------------------------
// Fused QKV GEMM (unchanged from round 7 — verified). V written transposed.
// ---------------------------------------------------------------------------
__global__ __launch_bounds__(256, 3) void qkv_gemm(
    const short* __restrict__ Xb, const short* __restrict__ Wt,
    const float* __restrict__ bq, const float* __restrict__ bk,
    const float* __restrict__ bv,
    short* __restrict__ Qb, short* __restrict__ Kb, short* __restrict__ Vt)
{
  __shared__ __align__(16) short SM[128 * 132];
  short (*A_lds)[64] = (short(*)[64])SM;
  short (*B_lds)[64] = (short(*)[64])(SM + 128 * 64);
  short (*Tv)[132]   = (short(*)[132])SM;

  const int tid = threadIdx.x;
  const int w  = tid >> 6;
  const int l  = tid & 63;
  const int lr = l & 15;
  const int g  = l >> 4;
  const int wm = w >> 1;
  const int wn = w & 1;

  const int raw = blockIdx.x;
  const int swz = (raw & 7) * 72 + (raw >> 3);
  const int by  = swz / 18;
  const int bx  = swz - by * 18;
  const int mb0 = by * 128;
  const int nb0 = bx * 128;

  const int lrow8 = l >> 3;
  const int lslot = (l & 7) ^ lrow8;
  const short* __restrict__ pA = Xb + (size_t)(mb0 + w * 32 + lrow8) * HID + lslot * 8;
  const short* __restrict__ pB = Wt + (size_t)(nb0 + w * 32 + lrow8) * HID + lslot * 8;

  f32x4 acc[4][4];
#pragma unroll
  for (int mi = 0; mi < 4; ++mi)
#pragma unroll
    for (int ni = 0; ni < 4; ++ni) acc[mi][ni] = (f32x4){0.f, 0.f, 0.f, 0.f};

  const int rsw = (lr & 7) << 3;

  for (int ks = 0; ks < HID / 64; ++ks) {
    const int k0 = ks * 64;
    __syncthreads();
#pragma unroll
    for (int i = 0; i < 4; ++i) {
      __builtin_amdgcn_global_load_lds(
          (const void*)(pA + k0 + i * 8 * HID), (void*)&A_lds[w * 32 + i * 8][0], 16, 0, 0);
      __builtin_amdgcn_global_load_lds(
          (const void*)(pB + k0 + i * 8 * HID), (void*)&B_lds[w * 32 + i * 8][0], 16, 0, 0);
    }
    __syncthreads();

#pragma unroll
    for (int h = 0; h < 2; ++h) {
      bf16x8 a[4], b[4];
#pragma unroll
      for (int i = 0; i < 4; ++i) {
        const int coff = (((h << 2) | g) << 3) ^ rsw;
        a[i] = *(const bf16x8*)&A_lds[wm * 64 + 16 * i + lr][coff];
        b[i] = *(const bf16x8*)&B_lds[wn * 64 + 16 * i + lr][coff];
      }
#pragma unroll
      for (int mi = 0; mi < 4; ++mi)
#pragma unroll
        for (int ni = 0; ni < 4; ++ni)
          acc[mi][ni] = __builtin_amdgcn_mfma_f32_16x16x32_bf16(a[mi], b[ni], acc[mi][ni], 0, 0, 0);
    }
  }

  const int mat  = nb0 / HID;
  const int n0   = nb0 + wn * 64;
  const int m0   = mb0 + wm * 64;
  const int colb = n0 - mat * HID;

  if (mat < 2) {
    const float* __restrict__ bias = (mat == 0) ? bq : bk;
    short* __restrict__ Out        = (mat == 0) ? Qb : Kb;
#pragma unroll
    for (int ni = 0; ni < 4; ++ni) {
      const int col = colb + 16 * ni + lr;
      const int h = col >> 6, d = col & 63;
      const float bias_v = bias[col];
#pragma unroll
      for (int mi = 0; mi < 4; ++mi) {
        const int mbase = m0 + 16 * mi + 4 * g;
#pragma unroll
        for (int r = 0; r < 4; ++r) {
          const int m = mbase + r;
          const int bb = m >> 11;
          const int s  = m & (SEQ - 1);
          Out[((size_t)(bb * NHEAD + h) * SEQ + s) * HD + d] = f2b(acc[mi][ni][r] + bias_v);
        }
      }
    }
  } else {
    __syncthreads();
#pragma unroll
    for (int ni = 0; ni < 4; ++ni) {
      const int col = colb + 16 * ni + lr;
      const float bias_v = bv[col];
      const int rowl = wn * 64 + 16 * ni + lr;
#pragma unroll
      for (int mi = 0; mi < 4; ++mi) {
        bf16x4 pk;
#pragma unroll
        for (int r = 0; r < 4; ++r) pk[r] = f2b(acc[mi][ni][r] + bias_v);
        *(bf16x4*)&Tv[rowl][wm * 64 + 16 * mi + 4 * g] = pk;
      }
    }
    __syncthreads();
    const int row  = tid >> 1;
    const int half = tid & 1;
    const int col  = nb0 - 2 * HID + row;
    const int h = col >> 6, d = col & 63;
    const int bb = mb0 >> 11;
    const int s0 = (mb0 & (SEQ - 1)) + half * 64;
    short* op = Vt + ((size_t)(bb * NHEAD + h) * HD + d) * SEQ + s0;
#pragma unroll
    for (int j = 0; j < 8; ++j)
      *(bf16x8*)(op + 8 * j) = *(const bf16x8*)&Tv[row][half * 64 + 8 * j];
  }
}

// ---------------------------------------------------------------------------
// Flash attention v9: v8 + dependency-chain surgery:
//  - QK and PV accumulation chains split 4-deep -> 2-deep (split accumulators)
//  - cross-half l shfl deferred out of the loop
//  - P cvt_pk+write reordered BEFORE the sum tree (hides ds_write latency)
// ---------------------------------------------------------------------------
__global__ __launch_bounds__(256, 3) void attn_fwd(
    const short* __restrict__ Qb, const short* __restrict__ Kb,
    const short* __restrict__ Vt, const float* __restrict__ mask2,
    float* __restrict__ out)
{
  __shared__ __align__(16) short KA[2][64][64];      // swizzled slots
  __shared__ __align__(16) short VA[2][64][64];      // swizzled slots
  __shared__ __align__(16) short PA[4][32][72];      // per-wave P [q][kv]

  const int tid  = threadIdx.x;
  const int w    = tid >> 6;         // wave 0..3
  const int pair = w >> 1;           // kv half
  const int pw   = w & 1;            // q half
  const int l    = tid & 63;
  const int r5   = l & 31;
  const int hi   = l >> 5;

  // XCD-locality remap: 768 blocks = 8 XCDs x (3 bh x 32 qblk)
  const int bid  = blockIdx.x;
  const int xcd  = bid & 7;
  const int slot = bid >> 3;         // 0..95
  const int bh   = xcd * 3 + (slot >> 5);
  const int qblk = slot & 31;

  const int b    = bh / 12;
  const int hh   = bh - b * 12;
  const int q0   = qblk * 64 + pw * 32;
  const int kb   = pair * 1024;      // kv base for this pair

  const short* __restrict__ Qh  = Qb + (size_t)bh * SEQ * HD;
  const short* __restrict__ Kh  = Kb + (size_t)bh * SEQ * HD;
  const short* __restrict__ Vth = Vt + (size_t)bh * HD * SEQ;
  const float* __restrict__ mb2 = mask2 + (size_t)b * SEQ;

  // Q fragments (B-operand): col q = r5, k(d) = 16j + 8hi + i
  bf16x8 qf[4];
#pragma unroll
  for (int j = 0; j < 4; ++j)
    qf[j] = *(const bf16x8*)(Qh + (size_t)(q0 + r5) * HD + 16 * j + 8 * hi);

  // split accumulators: each chain only 2 MFMAs deep per tile
  f32x16 o0a = (f32x16){0.f}, o0b = (f32x16){0.f};
  f32x16 o1a = (f32x16){0.f}, o1b = (f32x16){0.f};
  float lsum = 0.f;                  // per-lane partial; cross-half shfl deferred

  // pair-local staging: 128 threads cover K[64][64] + VT[64][64]
  const int ptid = tid & 127;
  const int sr = ptid >> 1;          // row 0..63
  const int sb = (ptid & 1) * 4;     // slot base (4 slots of 8 shorts)
  const short* __restrict__ Kp = Kh + (size_t)(kb + sr) * HD + sb * 8;
  const short* __restrict__ Vp = Vth + (size_t)sr * SEQ + kb + sb * 8;
  const int ssw = sr & 7;            // staging-row swizzle

  bf16x8 kst[4], vst[4];
#pragma unroll
  for (int j = 0; j < 4; ++j) {
    kst[j] = *(const bf16x8*)(Kp + 8 * j);
    vst[j] = *(const bf16x8*)(Vp + 8 * j);
  }
#pragma unroll
  for (int j = 0; j < 4; ++j) {
    *(bf16x8*)&KA[pair][sr][((sb + j) ^ ssw) * 8] = kst[j];
    *(bf16x8*)&VA[pair][sr][((sb + j) ^ ssw) * 8] = vst[j];
  }

  const int rsw = r5 & 7;            // read-row swizzle

  for (int t = 0; t < 16; ++t) {
    const int kv0 = kb + t * 64;
    __syncthreads();   // (1) staged writes of tile t visible

    // issue next tile's global loads (wrap within this pair's half)
    const size_t kvn = (size_t)(((t + 1) & 15) * 64);
#pragma unroll
    for (int j = 0; j < 4; ++j) {
      kst[j] = *(const bf16x8*)(Kp + kvn * HD + 8 * j);
      vst[j] = *(const bf16x8*)(Vp + kvn + 8 * j);
    }

    // S^T = K * Q^T : 4 independent 2-deep chains
    f32x16 s0a = (f32x16){0.f}, s0b = (f32x16){0.f};
    f32x16 s1a = (f32x16){0.f}, s1b = (f32x16){0.f};
    __builtin_amdgcn_s_setprio(1);
#pragma unroll
    for (int j = 0; j < 2; ++j) {
      const int co0 = ((2 * j + hi) ^ rsw) * 8;
      const int co1 = ((2 * (j + 2) + hi) ^ rsw) * 8;
      bf16x8 ka0a = *(const bf16x8*)&KA[pair][r5][co0];
      bf16x8 ka1a = *(const bf16x8*)&KA[pair][32 + r5][co0];
      bf16x8 ka0b = *(const bf16x8*)&KA[pair][r5][co1];
      bf16x8 ka1b = *(const bf16x8*)&KA[pair][32 + r5][co1];
      s0a = __builtin_amdgcn_mfma_f32_32x32x16_bf16(ka0a, qf[j], s0a, 0, 0, 0);
      s1a = __builtin_amdgcn_mfma_f32_32x32x16_bf16(ka1a, qf[j], s1a, 0, 0, 0);
      s0b = __builtin_amdgcn_mfma_f32_32x32x16_bf16(ka0b, qf[j + 2], s0b, 0, 0, 0);
      s1b = __builtin_amdgcn_mfma_f32_32x32x16_bf16(ka1b, qf[j + 2], s1b, 0, 0, 0);
    }
    __builtin_amdgcn_s_setprio(0);
    f32x16 st0 = s0a + s0b;
    f32x16 st1 = s1a + s1b;

    // fixed-max softmax: p = exp2(st*C1 + mask2[kv])
    float p[2][16];
#pragma unroll
    for (int t2 = 0; t2 < 4; ++t2) {
      f32x4 mv0 = *(const f32x4*)&mb2[kv0 + 8 * t2 + 4 * hi];
      f32x4 mv1 = *(const f32x4*)&mb2[kv0 + 32 + 8 * t2 + 4 * hi];
#pragma unroll
      for (int e = 0; e < 4; ++e) {
        p[0][4 * t2 + e] = fexp2(st0[4 * t2 + e] * C1 + mv0[e]);
        p[1][4 * t2 + e] = fexp2(st1[4 * t2 + e] * C1 + mv1[e]);
      }
    }

    // pack P -> bf16 -> wave-private LDS FIRST (write latency hides under tree)
#pragma unroll
    for (int s2 = 0; s2 < 2; ++s2)
#pragma unroll
      for (int t2 = 0; t2 < 4; ++t2) {
        unsigned int u0, u1;
        asm("v_cvt_pk_bf16_f32 %0, %1, %2"
            : "=v"(u0) : "v"(p[s2][4 * t2 + 0]), "v"(p[s2][4 * t2 + 1]));
        asm("v_cvt_pk_bf16_f32 %0, %1, %2"
            : "=v"(u1) : "v"(p[s2][4 * t2 + 2]), "v"(p[s2][4 * t2 + 3]));
        uint2 uv; uv.x = u0; uv.y = u1;
        *(uint2*)&PA[w][r5][32 * s2 + 8 * t2 + 4 * hi] = uv;
      }

    // per-lane sum tree (cross-half shfl deferred to after the loop)
    float sm[8];
#pragma unroll
    for (int i = 0; i < 8; ++i)
      sm[i] = (p[0][2 * i] + p[0][2 * i + 1]) + (p[1][2 * i] + p[1][2 * i + 1]);
    lsum += ((sm[0] + sm[1]) + (sm[2] + sm[3])) + ((sm[4] + sm[5]) + (sm[6] + sm[7]));

    bf16x8 pf[4];
#pragma unroll
    for (int j = 0; j < 4; ++j)
      pf[j] = *(const bf16x8*)&PA[w][r5][16 * j + 8 * hi];

    // O^T += V^T * P^T : split accumulators, 2-deep chains
    __builtin_amdgcn_s_setprio(1);
    {
      const int c0 = ((0 + hi) ^ rsw) * 8;
      const int c1 = ((2 + hi) ^ rsw) * 8;
      const int c2 = ((4 + hi) ^ rsw) * 8;
      const int c3 = ((6 + hi) ^ rsw) * 8;
      bf16x8 va00 = *(const bf16x8*)&VA[pair][r5][c0];
      bf16x8 va01 = *(const bf16x8*)&VA[pair][r5][c1];
      bf16x8 va02 = *(const bf16x8*)&VA[pair][r5][c2];
      bf16x8 va03 = *(const bf16x8*)&VA[pair][r5][c3];
      bf16x8 va10 = *(const bf16x8*)&VA[pair][32 + r5][c0];
      bf16x8 va11 = *(const bf16x8*)&VA[pair][32 + r5][c1];
      bf16x8 va12 = *(const bf16x8*)&VA[pair][32 + r5][c2];
      bf16x8 va13 = *(const bf16x8*)&VA[pair][32 + r5][c3];
      o0a = __builtin_amdgcn_mfma_f32_32x32x16_bf16(va00, pf[0], o0a, 0, 0, 0);
      o1a = __builtin_amdgcn_mfma_f32_32x32x16_bf16(va10, pf[0], o1a, 0, 0, 0);
      o0b = __builtin_amdgcn_mfma_f32_32x32x16_bf16(va02, pf[2], o0b, 0, 0, 0);
      o1b = __builtin_amdgcn_mfma_f32_32x32x16_bf16(va12, pf[2], o1b, 0, 0, 0);
      o0a = __builtin_amdgcn_mfma_f32_32x32x16_bf16(va01, pf[1], o0a, 0, 0, 0);
      o1a = __builtin_amdgcn_mfma_f32_32x32x16_bf16(va11, pf[1], o1a, 0, 0, 0);
      o0b = __builtin_amdgcn_mfma_f32_32x32x16_bf16(va03, pf[3], o0b, 0, 0, 0);
      o1b = __builtin_amdgcn_mfma_f32_32x32x16_bf16(va13, pf[3], o1b, 0, 0, 0);
    }
    __builtin_amdgcn_s_setprio(0);

    __syncthreads();   // (2) all reads of tile t done -> safe to overwrite
#pragma unroll
    for (int j = 0; j < 4; ++j) {
      *(bf16x8*)&KA[pair][sr][((sb + j) ^ ssw) * 8] = kst[j];
      *(bf16x8*)&VA[pair][sr][((sb + j) ^ ssw) * 8] = vst[j];
    }
  }

  // finalize: combine split accumulators + deferred cross-half reduce
  f32x16 o0 = o0a + o0b;
  f32x16 o1 = o1a + o1b;
  const float l_run = lsum + __shfl_xor(lsum, 32, 64);

  // ---- cross-pair merge: waves 2,3 publish (l,O); waves 0,1 combine ----
  __syncthreads();
  float* Os = (float*)&KA[0][0][0];   // [2][32][64] f32 = 16384 B, fits KA
  float* ML = (float*)&PA[0][0][0];   // [2][32] f32 in dead PA region

  if (w >= 2) {
    const int wv = w - 2;
    float* Or = Os + (size_t)(wv * 32 + r5) * 64;
#pragma unroll
    for (int t2 = 0; t2 < 4; ++t2) {
      f32x4 v0, v1;
#pragma unroll
      for (int e = 0; e < 4; ++e) { v0[e] = o0[4 * t2 + e]; v1[e] = o1[4 * t2 + e]; }
      *(f32x4*)&Or[8 * t2 + 4 * hi]      = v0;
      *(f32x4*)&Or[32 + 8 * t2 + 4 * hi] = v1;
    }
    if (hi == 0) ML[wv * 32 + r5] = l_run;
  }
  __syncthreads();
  if (w < 2) {
    const float lo  = ML[w * 32 + r5];
    const float inv = 1.f / (l_run + lo);
    const float* Or = Os + (size_t)(w * 32 + r5) * 64;
    float* ob = out + (size_t)(b * SEQ + q0 + r5) * HID + hh * HD;
#pragma unroll
    for (int t2 = 0; t2 < 4; ++t2) {
      f32x4 po = *(const f32x4*)&Or[8 * t2 + 4 * hi];
      f32x4 p1 = *(const f32x4*)&Or[32 + 8 * t2 + 4 * hi];
      f32x4 v0, v1;
#pragma unroll
      for (int e = 0; e < 4; ++e) {
        v0[e] = (o0[4 * t2 + e] + po[e]) * inv;
        v1[e] = (o1[4 * t2 + e] + p1[e]) * inv;
      }
      *(f32x4*)&ob[8 * t2 + 4 * hi]      = v0;
      *(f32x4*)&ob[32 + 8 * t2 + 4 * hi] = v1;
    }
  }
}

// ---------------------------------------------------------------------------
extern "C" void kernel_launch(void* const* d_in, const int* in_sizes, int n_in,
                              void* d_out, int out_size, void* d_ws, size_t ws_size,
                              hipStream_t stream) {
  const float* X    = (const float*)d_in[0];
  const float* mask = (const float*)d_in[1];
  const float* Wq   = (const float*)d_in[2];
  const float* bq   = (const float*)d_in[3];
  const float* Wk   = (const float*)d_in[4];
  const float* bk   = (const float*)d_in[5];
  const float* Wv   = (const float*)d_in[6];
  const float* bv   = (const float*)d_in[7];
  float* out = (float*)d_out;

  short* Qb = (short*)d_ws;
  short* Kb = Qb + PH;
  short* Vt = Kb + PH;                 // V stored transposed [bh][d][s]
  short* Xb = Vt + PH;
  short* Wt = Xb + XEL;
  float* mask2 = (float*)(Wt + (size_t)3 * HID * HID);

  prep<<<dim3(1201), 256, 0, stream>>>(X, Wq, Wk, Wv, mask, Xb, Wt, mask2);
  qkv_gemm<<<dim3(576), 256, 0, stream>>>(Xb, Wt, bq, bk, bv, Qb, Kb, Vt);
  attn_fwd<<<dim3(768), 256, 0, stream>>>(Qb, Kb, Vt, mask2, out);
}

// Round 18
// 84.741 us; speedup vs baseline: 2.1602x; 2.1602x over previous
//
#include <hip/hip_runtime.h>

#define HID 768
#define NHEAD 12
#define HD 64
#define SEQ 2048
#define BATCH 2
#define PH (BATCH * NHEAD * SEQ * HD)   // 3,145,728 elements per Q/K/V plane
#define XEL (BATCH * SEQ * HID)
#define LOG2E 1.4426950408889634f
#define C1 (0.125f * LOG2E)             // QK scale folded with log2e
#define FMAX2 16.0f                     // fixed softmax max (log2 domain)

typedef __attribute__((ext_vector_type(8))) short bf16x8;
typedef __attribute__((ext_vector_type(4))) short bf16x4;
typedef __attribute__((ext_vector_type(4))) float f32x4;
typedef __attribute__((ext_vector_type(16))) float f32x16;

static __device__ __forceinline__ short f2b(float f) {
  unsigned int u = __builtin_bit_cast(unsigned int, f);
  unsigned int r = (u + 0x7fffu + ((u >> 16) & 1u)) >> 16;
  return (short)(unsigned short)r;
}

static __device__ __forceinline__ float fexp2(float x) {
  float r; asm("v_exp_f32 %0, %1" : "=v"(r) : "v"(x)); return r;
}

// ---------------------------------------------------------------------------
// Prep: X->bf16, W transpose->Wt[n][k] bf16, mask2 = mask*log2e - FMAX2
// ---------------------------------------------------------------------------
__global__ __launch_bounds__(256) void prep(
    const float* __restrict__ X,
    const float* __restrict__ Wq, const float* __restrict__ Wk,
    const float* __restrict__ Wv, const float* __restrict__ mask,
    short* __restrict__ Xb, short* __restrict__ Wt, float* __restrict__ mask2)
{
  __shared__ short T[64][65];
  const int t = threadIdx.x;
  const int blk = blockIdx.x;
  if (blk < 768) {
    const size_t base = (size_t)blk * 4096 + t * 16;
    f32x4 a0 = *(const f32x4*)(X + base);
    f32x4 a1 = *(const f32x4*)(X + base + 4);
    f32x4 a2 = *(const f32x4*)(X + base + 8);
    f32x4 a3 = *(const f32x4*)(X + base + 12);
    bf16x8 o0, o1;
#pragma unroll
    for (int i = 0; i < 4; ++i) {
      o0[i] = f2b(a0[i]); o0[4 + i] = f2b(a1[i]);
      o1[i] = f2b(a2[i]); o1[4 + i] = f2b(a3[i]);
    }
    *(bf16x8*)(Xb + base) = o0;
    *(bf16x8*)(Xb + base + 8) = o1;
  } else if (blk < 1200) {
    const int wb   = blk - 768;
    const int mat  = wb / 144;
    const int tile = wb - mat * 144;
    const int r0 = (tile / 12) * 64;
    const int c0 = (tile % 12) * 64;
    const float* __restrict__ W = (mat == 0) ? Wq : (mat == 1 ? Wk : Wv);
#pragma unroll
    for (int i = 0; i < 4; ++i) {
      const int r = (t >> 4) + 16 * i;
      const int c = (t & 15) * 4;
      f32x4 v = *(const f32x4*)(W + (size_t)(r0 + r) * HID + c0 + c);
      T[r][c + 0] = f2b(v[0]); T[r][c + 1] = f2b(v[1]);
      T[r][c + 2] = f2b(v[2]); T[r][c + 3] = f2b(v[3]);
    }
    __syncthreads();
    const int cr = t >> 2;
    const int ck = (t & 3) * 16;
    bf16x8 u0, u1;
#pragma unroll
    for (int j = 0; j < 8; ++j) { u0[j] = T[ck + j][cr]; u1[j] = T[ck + 8 + j][cr]; }
    short* orow = Wt + (size_t)(mat * HID + c0 + cr) * HID + r0 + ck;
    *(bf16x8*)orow = u0;
    *(bf16x8*)(orow + 8) = u1;
  } else {
#pragma unroll
    for (int i = 0; i < 4; ++i) {
      const int idx = (t * 4 + i * 1024);
      f32x4 v = *(const f32x4*)(mask + idx);
      v = v * LOG2E - FMAX2;
      *(f32x4*)(mask2 + idx) = v;
    }
  }
}

// ---------------------------------------------------------------------------
// Fused QKV GEMM (unchanged from round 7 — verified). V written transposed.
// ---------------------------------------------------------------------------
__global__ __launch_bounds__(256, 3) void qkv_gemm(
    const short* __restrict__ Xb, const short* __restrict__ Wt,
    const float* __restrict__ bq, const float* __restrict__ bk,
    const float* __restrict__ bv,
    short* __restrict__ Qb, short* __restrict__ Kb, short* __restrict__ Vt)
{
  __shared__ __align__(16) short SM[128 * 132];
  short (*A_lds)[64] = (short(*)[64])SM;
  short (*B_lds)[64] = (short(*)[64])(SM + 128 * 64);
  short (*Tv)[132]   = (short(*)[132])SM;

  const int tid = threadIdx.x;
  const int w  = tid >> 6;
  const int l  = tid & 63;
  const int lr = l & 15;
  const int g  = l >> 4;
  const int wm = w >> 1;
  const int wn = w & 1;

  const int raw = blockIdx.x;
  const int swz = (raw & 7) * 72 + (raw >> 3);
  const int by  = swz / 18;
  const int bx  = swz - by * 18;
  const int mb0 = by * 128;
  const int nb0 = bx * 128;

  const int lrow8 = l >> 3;
  const int lslot = (l & 7) ^ lrow8;
  const short* __restrict__ pA = Xb + (size_t)(mb0 + w * 32 + lrow8) * HID + lslot * 8;
  const short* __restrict__ pB = Wt + (size_t)(nb0 + w * 32 + lrow8) * HID + lslot * 8;

  f32x4 acc[4][4];
#pragma unroll
  for (int mi = 0; mi < 4; ++mi)
#pragma unroll
    for (int ni = 0; ni < 4; ++ni) acc[mi][ni] = (f32x4){0.f, 0.f, 0.f, 0.f};

  const int rsw = (lr & 7) << 3;

  for (int ks = 0; ks < HID / 64; ++ks) {
    const int k0 = ks * 64;
    __syncthreads();
#pragma unroll
    for (int i = 0; i < 4; ++i) {
      __builtin_amdgcn_global_load_lds(
          (const void*)(pA + k0 + i * 8 * HID), (void*)&A_lds[w * 32 + i * 8][0], 16, 0, 0);
      __builtin_amdgcn_global_load_lds(
          (const void*)(pB + k0 + i * 8 * HID), (void*)&B_lds[w * 32 + i * 8][0], 16, 0, 0);
    }
    __syncthreads();

#pragma unroll
    for (int h = 0; h < 2; ++h) {
      bf16x8 a[4], b[4];
#pragma unroll
      for (int i = 0; i < 4; ++i) {
        const int coff = (((h << 2) | g) << 3) ^ rsw;
        a[i] = *(const bf16x8*)&A_lds[wm * 64 + 16 * i + lr][coff];
        b[i] = *(const bf16x8*)&B_lds[wn * 64 + 16 * i + lr][coff];
      }
#pragma unroll
      for (int mi = 0; mi < 4; ++mi)
#pragma unroll
        for (int ni = 0; ni < 4; ++ni)
          acc[mi][ni] = __builtin_amdgcn_mfma_f32_16x16x32_bf16(a[mi], b[ni], acc[mi][ni], 0, 0, 0);
    }
  }

  const int mat  = nb0 / HID;
  const int n0   = nb0 + wn * 64;
  const int m0   = mb0 + wm * 64;
  const int colb = n0 - mat * HID;

  if (mat < 2) {
    const float* __restrict__ bias = (mat == 0) ? bq : bk;
    short* __restrict__ Out        = (mat == 0) ? Qb : Kb;
#pragma unroll
    for (int ni = 0; ni < 4; ++ni) {
      const int col = colb + 16 * ni + lr;
      const int h = col >> 6, d = col & 63;
      const float bias_v = bias[col];
#pragma unroll
      for (int mi = 0; mi < 4; ++mi) {
        const int mbase = m0 + 16 * mi + 4 * g;
#pragma unroll
        for (int r = 0; r < 4; ++r) {
          const int m = mbase + r;
          const int bb = m >> 11;
          const int s  = m & (SEQ - 1);
          Out[((size_t)(bb * NHEAD + h) * SEQ + s) * HD + d] = f2b(acc[mi][ni][r] + bias_v);
        }
      }
    }
  } else {
    __syncthreads();
#pragma unroll
    for (int ni = 0; ni < 4; ++ni) {
      const int col = colb + 16 * ni + lr;
      const float bias_v = bv[col];
      const int rowl = wn * 64 + 16 * ni + lr;
#pragma unroll
      for (int mi = 0; mi < 4; ++mi) {
        bf16x4 pk;
#pragma unroll
        for (int r = 0; r < 4; ++r) pk[r] = f2b(acc[mi][ni][r] + bias_v);
        *(bf16x4*)&Tv[rowl][wm * 64 + 16 * mi + 4 * g] = pk;
      }
    }
    __syncthreads();
    const int row  = tid >> 1;
    const int half = tid & 1;
    const int col  = nb0 - 2 * HID + row;
    const int h = col >> 6, d = col & 63;
    const int bb = mb0 >> 11;
    const int s0 = (mb0 & (SEQ - 1)) + half * 64;
    short* op = Vt + ((size_t)(bb * NHEAD + h) * HD + d) * SEQ + s0;
#pragma unroll
    for (int j = 0; j < 8; ++j)
      *(bf16x8*)(op + 8 * j) = *(const bf16x8*)&Tv[row][half * 64 + 8 * j];
  }
}

// ---------------------------------------------------------------------------
// Flash attention v10: round-16 structure (verified 63.5 us, VGPR 84) +
// ONLY the register-neutral chain tweaks:
//  - cross-half l shfl deferred out of the loop (lsum, one shfl at end)
//  - cvt_pk + P-write placed BEFORE the sum tree (ds_write latency hidden)
// NO accumulator splits (round-17 spill lesson).
// ---------------------------------------------------------------------------
__global__ __launch_bounds__(256, 3) void attn_fwd(
    const short* __restrict__ Qb, const short* __restrict__ Kb,
    const short* __restrict__ Vt, const float* __restrict__ mask2,
    float* __restrict__ out)
{
  __shared__ __align__(16) short KA[2][64][64];      // swizzled slots
  __shared__ __align__(16) short VA[2][64][64];      // swizzled slots
  __shared__ __align__(16) short PA[4][32][72];      // per-wave P [q][kv]

  const int tid  = threadIdx.x;
  const int w    = tid >> 6;         // wave 0..3
  const int pair = w >> 1;           // kv half
  const int pw   = w & 1;            // q half
  const int l    = tid & 63;
  const int r5   = l & 31;
  const int hi   = l >> 5;

  // XCD-locality remap: 768 blocks = 8 XCDs x (3 bh x 32 qblk)
  const int bid  = blockIdx.x;
  const int xcd  = bid & 7;
  const int slot = bid >> 3;         // 0..95
  const int bh   = xcd * 3 + (slot >> 5);
  const int qblk = slot & 31;

  const int b    = bh / 12;
  const int hh   = bh - b * 12;
  const int q0   = qblk * 64 + pw * 32;
  const int kb   = pair * 1024;      // kv base for this pair

  const short* __restrict__ Qh  = Qb + (size_t)bh * SEQ * HD;
  const short* __restrict__ Kh  = Kb + (size_t)bh * SEQ * HD;
  const short* __restrict__ Vth = Vt + (size_t)bh * HD * SEQ;
  const float* __restrict__ mb2 = mask2 + (size_t)b * SEQ;

  // Q fragments (B-operand): col q = r5, k(d) = 16j + 8hi + i
  bf16x8 qf[4];
#pragma unroll
  for (int j = 0; j < 4; ++j)
    qf[j] = *(const bf16x8*)(Qh + (size_t)(q0 + r5) * HD + 16 * j + 8 * hi);

  f32x16 o0 = (f32x16){0.f};
  f32x16 o1 = (f32x16){0.f};
  float lsum = 0.f;                  // per-lane partial; cross-half shfl deferred

  // pair-local staging: 128 threads cover K[64][64] + VT[64][64]
  const int ptid = tid & 127;
  const int sr = ptid >> 1;          // row 0..63
  const int sb = (ptid & 1) * 4;     // slot base (4 slots of 8 shorts)
  const short* __restrict__ Kp = Kh + (size_t)(kb + sr) * HD + sb * 8;
  const short* __restrict__ Vp = Vth + (size_t)sr * SEQ + kb + sb * 8;
  const int ssw = sr & 7;            // staging-row swizzle

  bf16x8 kst[4], vst[4];
#pragma unroll
  for (int j = 0; j < 4; ++j) {
    kst[j] = *(const bf16x8*)(Kp + 8 * j);
    vst[j] = *(const bf16x8*)(Vp + 8 * j);
  }
#pragma unroll
  for (int j = 0; j < 4; ++j) {
    *(bf16x8*)&KA[pair][sr][((sb + j) ^ ssw) * 8] = kst[j];
    *(bf16x8*)&VA[pair][sr][((sb + j) ^ ssw) * 8] = vst[j];
  }

  const int rsw = r5 & 7;            // read-row swizzle

  for (int t = 0; t < 16; ++t) {
    const int kv0 = kb + t * 64;
    __syncthreads();   // (1) staged writes of tile t visible

    // issue next tile's global loads (wrap within this pair's half)
    const size_t kvn = (size_t)(((t + 1) & 15) * 64);
#pragma unroll
    for (int j = 0; j < 4; ++j) {
      kst[j] = *(const bf16x8*)(Kp + kvn * HD + 8 * j);
      vst[j] = *(const bf16x8*)(Vp + kvn + 8 * j);
    }

    // S^T = K * Q^T : 2 kv-subtiles x 4 chained (d) 32x32x16 MFMAs
    f32x16 st0 = (f32x16){0.f};
    f32x16 st1 = (f32x16){0.f};
    __builtin_amdgcn_s_setprio(1);
#pragma unroll
    for (int j = 0; j < 4; ++j) {
      const int co = ((2 * j + hi) ^ rsw) * 8;
      bf16x8 ka0 = *(const bf16x8*)&KA[pair][r5][co];
      bf16x8 ka1 = *(const bf16x8*)&KA[pair][32 + r5][co];
      st0 = __builtin_amdgcn_mfma_f32_32x32x16_bf16(ka0, qf[j], st0, 0, 0, 0);
      st1 = __builtin_amdgcn_mfma_f32_32x32x16_bf16(ka1, qf[j], st1, 0, 0, 0);
    }
    __builtin_amdgcn_s_setprio(0);

    // fixed-max softmax: p = exp2(st*C1 + mask2[kv]) (mask2 pre-shifted -16)
    float p[2][16];
#pragma unroll
    for (int t2 = 0; t2 < 4; ++t2) {
      f32x4 mv0 = *(const f32x4*)&mb2[kv0 + 8 * t2 + 4 * hi];
      f32x4 mv1 = *(const f32x4*)&mb2[kv0 + 32 + 8 * t2 + 4 * hi];
#pragma unroll
      for (int e = 0; e < 4; ++e) {
        p[0][4 * t2 + e] = fexp2(st0[4 * t2 + e] * C1 + mv0[e]);
        p[1][4 * t2 + e] = fexp2(st1[4 * t2 + e] * C1 + mv1[e]);
      }
    }

    // pack P -> bf16 -> wave-private LDS FIRST (write latency hides under tree)
#pragma unroll
    for (int s2 = 0; s2 < 2; ++s2)
#pragma unroll
      for (int t2 = 0; t2 < 4; ++t2) {
        unsigned int u0, u1;
        asm("v_cvt_pk_bf16_f32 %0, %1, %2"
            : "=v"(u0) : "v"(p[s2][4 * t2 + 0]), "v"(p[s2][4 * t2 + 1]));
        asm("v_cvt_pk_bf16_f32 %0, %1, %2"
            : "=v"(u1) : "v"(p[s2][4 * t2 + 2]), "v"(p[s2][4 * t2 + 3]));
        uint2 uv; uv.x = u0; uv.y = u1;
        *(uint2*)&PA[w][r5][32 * s2 + 8 * t2 + 4 * hi] = uv;
      }

    // per-lane sum tree (cross-half shfl deferred to after the loop)
    float sm[8];
#pragma unroll
    for (int i = 0; i < 8; ++i)
      sm[i] = (p[0][2 * i] + p[0][2 * i + 1]) + (p[1][2 * i] + p[1][2 * i + 1]);
    lsum += ((sm[0] + sm[1]) + (sm[2] + sm[3])) + ((sm[4] + sm[5]) + (sm[6] + sm[7]));

    bf16x8 pf[4];
#pragma unroll
    for (int j = 0; j < 4; ++j)
      pf[j] = *(const bf16x8*)&PA[w][r5][16 * j + 8 * hi];

    // O^T += V^T * P^T
    __builtin_amdgcn_s_setprio(1);
#pragma unroll
    for (int j = 0; j < 4; ++j) {
      const int co = ((2 * j + hi) ^ rsw) * 8;
      bf16x8 va0 = *(const bf16x8*)&VA[pair][r5][co];
      bf16x8 va1 = *(const bf16x8*)&VA[pair][32 + r5][co];
      o0 = __builtin_amdgcn_mfma_f32_32x32x16_bf16(va0, pf[j], o0, 0, 0, 0);
      o1 = __builtin_amdgcn_mfma_f32_32x32x16_bf16(va1, pf[j], o1, 0, 0, 0);
    }
    __builtin_amdgcn_s_setprio(0);

    __syncthreads();   // (2) all reads of tile t done -> safe to overwrite
#pragma unroll
    for (int j = 0; j < 4; ++j) {
      *(bf16x8*)&KA[pair][sr][((sb + j) ^ ssw) * 8] = kst[j];
      *(bf16x8*)&VA[pair][sr][((sb + j) ^ ssw) * 8] = vst[j];
    }
  }

  // deferred cross-half reduce
  const float l_run = lsum + __shfl_xor(lsum, 32, 64);

  // ---- cross-pair merge: waves 2,3 publish (l,O); waves 0,1 combine ----
  __syncthreads();
  float* Os = (float*)&KA[0][0][0];   // [2][32][64] f32 = 16384 B, fits KA
  float* ML = (float*)&PA[0][0][0];   // [2][32] f32 in dead PA region

  if (w >= 2) {
    const int wv = w - 2;
    float* Or = Os + (size_t)(wv * 32 + r5) * 64;
#pragma unroll
    for (int t2 = 0; t2 < 4; ++t2) {
      f32x4 v0, v1;
#pragma unroll
      for (int e = 0; e < 4; ++e) { v0[e] = o0[4 * t2 + e]; v1[e] = o1[4 * t2 + e]; }
      *(f32x4*)&Or[8 * t2 + 4 * hi]      = v0;
      *(f32x4*)&Or[32 + 8 * t2 + 4 * hi] = v1;
    }
    if (hi == 0) ML[wv * 32 + r5] = l_run;
  }
  __syncthreads();
  if (w < 2) {
    const float lo  = ML[w * 32 + r5];
    const float inv = 1.f / (l_run + lo);
    const float* Or = Os + (size_t)(w * 32 + r5) * 64;
    float* ob = out + (size_t)(b * SEQ + q0 + r5) * HID + hh * HD;
#pragma unroll
    for (int t2 = 0; t2 < 4; ++t2) {
      f32x4 po = *(const f32x4*)&Or[8 * t2 + 4 * hi];
      f32x4 p1 = *(const f32x4*)&Or[32 + 8 * t2 + 4 * hi];
      f32x4 v0, v1;
#pragma unroll
      for (int e = 0; e < 4; ++e) {
        v0[e] = (o0[4 * t2 + e] + po[e]) * inv;
        v1[e] = (o1[4 * t2 + e] + p1[e]) * inv;
      }
      *(f32x4*)&ob[8 * t2 + 4 * hi]      = v0;
      *(f32x4*)&ob[32 + 8 * t2 + 4 * hi] = v1;
    }
  }
}

// ---------------------------------------------------------------------------
extern "C" void kernel_launch(void* const* d_in, const int* in_sizes, int n_in,
                              void* d_out, int out_size, void* d_ws, size_t ws_size,
                              hipStream_t stream) {
  const float* X    = (const float*)d_in[0];
  const float* mask = (const float*)d_in[1];
  const float* Wq   = (const float*)d_in[2];
  const float* bq   = (const float*)d_in[3];
  const float* Wk   = (const float*)d_in[4];
  const float* bk   = (const float*)d_in[5];
  const float* Wv   = (const float*)d_in[6];
  const float* bv   = (const float*)d_in[7];
  float* out = (float*)d_out;

  short* Qb = (short*)d_ws;
  short* Kb = Qb + PH;
  short* Vt = Kb + PH;                 // V stored transposed [bh][d][s]
  short* Xb = Vt + PH;
  short* Wt = Xb + XEL;
  float* mask2 = (float*)(Wt + (size_t)3 * HID * HID);

  prep<<<dim3(1201), 256, 0, stream>>>(X, Wq, Wk, Wv, mask, Xb, Wt, mask2);
  qkv_gemm<<<dim3(576), 256, 0, stream>>>(Xb, Wt, bq, bk, bv, Qb, Kb, Vt);
  attn_fwd<<<dim3(768), 256, 0, stream>>>(Qb, Kb, Vt, mask2, out);
}

// Round 19
// 82.592 us; speedup vs baseline: 2.2164x; 1.0260x over previous
//
#include <hip/hip_runtime.h>

#define HID 768
#define NHEAD 12
#define HD 64
#define SEQ 2048
#define BATCH 2
#define PH (BATCH * NHEAD * SEQ * HD)   // 3,145,728 elements per Q/K/V plane
#define XEL (BATCH * SEQ * HID)
#define LOG2E 1.4426950408889634f
#define C1 (0.125f * LOG2E)             // QK scale folded with log2e
#define FMAX2 16.0f                     // fixed softmax max (log2 domain)

typedef __attribute__((ext_vector_type(8))) short bf16x8;
typedef __attribute__((ext_vector_type(4))) short bf16x4;
typedef __attribute__((ext_vector_type(4))) float f32x4;
typedef __attribute__((ext_vector_type(16))) float f32x16;

static __device__ __forceinline__ short f2b(float f) {
  unsigned int u = __builtin_bit_cast(unsigned int, f);
  unsigned int r = (u + 0x7fffu + ((u >> 16) & 1u)) >> 16;
  return (short)(unsigned short)r;
}

static __device__ __forceinline__ float fexp2(float x) {
  float r; asm("v_exp_f32 %0, %1" : "=v"(r) : "v"(x)); return r;
}

// ---------------------------------------------------------------------------
// Prep (byte-identical to round 18): X->bf16, W->Wt bf16, mask2 = m*log2e-16
// ---------------------------------------------------------------------------
__global__ __launch_bounds__(256) void prep(
    const float* __restrict__ X,
    const float* __restrict__ Wq, const float* __restrict__ Wk,
    const float* __restrict__ Wv, const float* __restrict__ mask,
    short* __restrict__ Xb, short* __restrict__ Wt, float* __restrict__ mask2)
{
  __shared__ short T[64][65];
  const int t = threadIdx.x;
  const int blk = blockIdx.x;
  if (blk < 768) {
    const size_t base = (size_t)blk * 4096 + t * 16;
    f32x4 a0 = *(const f32x4*)(X + base);
    f32x4 a1 = *(const f32x4*)(X + base + 4);
    f32x4 a2 = *(const f32x4*)(X + base + 8);
    f32x4 a3 = *(const f32x4*)(X + base + 12);
    bf16x8 o0, o1;
#pragma unroll
    for (int i = 0; i < 4; ++i) {
      o0[i] = f2b(a0[i]); o0[4 + i] = f2b(a1[i]);
      o1[i] = f2b(a2[i]); o1[4 + i] = f2b(a3[i]);
    }
    *(bf16x8*)(Xb + base) = o0;
    *(bf16x8*)(Xb + base + 8) = o1;
  } else if (blk < 1200) {
    const int wb   = blk - 768;
    const int mat  = wb / 144;
    const int tile = wb - mat * 144;
    const int r0 = (tile / 12) * 64;
    const int c0 = (tile % 12) * 64;
    const float* __restrict__ W = (mat == 0) ? Wq : (mat == 1 ? Wk : Wv);
#pragma unroll
    for (int i = 0; i < 4; ++i) {
      const int r = (t >> 4) + 16 * i;
      const int c = (t & 15) * 4;
      f32x4 v = *(const f32x4*)(W + (size_t)(r0 + r) * HID + c0 + c);
      T[r][c + 0] = f2b(v[0]); T[r][c + 1] = f2b(v[1]);
      T[r][c + 2] = f2b(v[2]); T[r][c + 3] = f2b(v[3]);
    }
    __syncthreads();
    const int cr = t >> 2;
    const int ck = (t & 3) * 16;
    bf16x8 u0, u1;
#pragma unroll
    for (int j = 0; j < 8; ++j) { u0[j] = T[ck + j][cr]; u1[j] = T[ck + 8 + j][cr]; }
    short* orow = Wt + (size_t)(mat * HID + c0 + cr) * HID + r0 + ck;
    *(bf16x8*)orow = u0;
    *(bf16x8*)(orow + 8) = u1;
  } else {
#pragma unroll
    for (int i = 0; i < 4; ++i) {
      const int idx = (t * 4 + i * 1024);
      f32x4 v = *(const f32x4*)(mask + idx);
      v = v * LOG2E - FMAX2;
      *(f32x4*)(mask2 + idx) = v;
    }
  }
}

// ---------------------------------------------------------------------------
// Fused QKV GEMM v2: tile 128x96, grid 768 = 3.0 blocks/CU EXACT (no tail).
// Wave tile 64x48 (acc 4x3). Same verified staging swizzle + frag labeling.
// 96 = 8 n-tiles per matrix exactly -> mat block-uniform. V written transposed.
// ---------------------------------------------------------------------------
__global__ __launch_bounds__(256, 3) void qkv_gemm(
    const short* __restrict__ Xb, const short* __restrict__ Wt,
    const float* __restrict__ bq, const float* __restrict__ bk,
    const float* __restrict__ bv,
    short* __restrict__ Qb, short* __restrict__ Kb, short* __restrict__ Vt)
{
  // staging: A[128][64] (16 KB) + B[96][64] (12 KB) = 28 KB; Tv[96][132] aliases
  __shared__ __align__(16) short SM[128 * 64 + 96 * 64];
  short (*A_lds)[64] = (short(*)[64])SM;
  short (*B_lds)[64] = (short(*)[64])(SM + 128 * 64);
  short (*Tv)[132]   = (short(*)[132])SM;

  const int tid = threadIdx.x;
  const int w  = tid >> 6;
  const int l  = tid & 63;
  const int lr = l & 15;
  const int g  = l >> 4;
  const int wm = w >> 1;
  const int wn = w & 1;

  // XCD-chunked bijective swizzle: 768 = 8 XCDs x 96 tiles
  const int raw = blockIdx.x;
  const int swz = (raw & 7) * 96 + (raw >> 3);
  const int by  = swz / 24;          // m-tile 0..31
  const int bx  = swz - by * 24;     // n-tile 0..23
  const int mb0 = by * 128;
  const int nb0 = bx * 96;

  const int lrow8 = l >> 3;
  const int lslot = (l & 7) ^ lrow8;
  const short* __restrict__ pA = Xb + (size_t)(mb0 + w * 32 + lrow8) * HID + lslot * 8;
  const short* __restrict__ pB = Wt + (size_t)(nb0 + w * 24 + lrow8) * HID + lslot * 8;

  f32x4 acc[4][3];
#pragma unroll
  for (int mi = 0; mi < 4; ++mi)
#pragma unroll
    for (int ni = 0; ni < 3; ++ni) acc[mi][ni] = (f32x4){0.f, 0.f, 0.f, 0.f};

  const int rsw = (lr & 7) << 3;

  for (int ks = 0; ks < HID / 64; ++ks) {
    const int k0 = ks * 64;
    __syncthreads();
#pragma unroll
    for (int i = 0; i < 4; ++i)
      __builtin_amdgcn_global_load_lds(
          (const void*)(pA + k0 + i * 8 * HID), (void*)&A_lds[w * 32 + i * 8][0], 16, 0, 0);
#pragma unroll
    for (int i = 0; i < 3; ++i)
      __builtin_amdgcn_global_load_lds(
          (const void*)(pB + k0 + i * 8 * HID), (void*)&B_lds[w * 24 + i * 8][0], 16, 0, 0);
    __syncthreads();

#pragma unroll
    for (int h = 0; h < 2; ++h) {
      const int coff = (((h << 2) | g) << 3) ^ rsw;
      bf16x8 a[4], b[3];
#pragma unroll
      for (int i = 0; i < 4; ++i)
        a[i] = *(const bf16x8*)&A_lds[wm * 64 + 16 * i + lr][coff];
#pragma unroll
      for (int i = 0; i < 3; ++i)
        b[i] = *(const bf16x8*)&B_lds[wn * 48 + 16 * i + lr][coff];
#pragma unroll
      for (int mi = 0; mi < 4; ++mi)
#pragma unroll
        for (int ni = 0; ni < 3; ++ni)
          acc[mi][ni] = __builtin_amdgcn_mfma_f32_16x16x32_bf16(a[mi], b[ni], acc[mi][ni], 0, 0, 0);
    }
  }

  const int mat  = bx >> 3;              // 8 n-tiles per matrix, block-uniform
  const int n0   = nb0 + wn * 48;
  const int m0   = mb0 + wm * 64;
  const int colb = n0 - mat * HID;

  if (mat < 2) {
    const float* __restrict__ bias = (mat == 0) ? bq : bk;
    short* __restrict__ Out        = (mat == 0) ? Qb : Kb;
#pragma unroll
    for (int ni = 0; ni < 3; ++ni) {
      const int col = colb + 16 * ni + lr;
      const int h = col >> 6, d = col & 63;
      const float bias_v = bias[col];
#pragma unroll
      for (int mi = 0; mi < 4; ++mi) {
        const int mbase = m0 + 16 * mi + 4 * g;
#pragma unroll
        for (int r = 0; r < 4; ++r) {
          const int m = mbase + r;
          const int bb = m >> 11;
          const int s  = m & (SEQ - 1);
          Out[((size_t)(bb * NHEAD + h) * SEQ + s) * HD + d] = f2b(acc[mi][ni][r] + bias_v);
        }
      }
    }
  } else {
    __syncthreads();   // all waves done reading staging LDS before Tv reuse
#pragma unroll
    for (int ni = 0; ni < 3; ++ni) {
      const int col = colb + 16 * ni + lr;
      const float bias_v = bv[col];
      const int rowl = wn * 48 + 16 * ni + lr;   // n within block tile, 0..95
#pragma unroll
      for (int mi = 0; mi < 4; ++mi) {
        bf16x4 pk;
#pragma unroll
        for (int r = 0; r < 4; ++r) pk[r] = f2b(acc[mi][ni][r] + bias_v);
        *(bf16x4*)&Tv[rowl][wm * 64 + 16 * mi + 4 * g] = pk;
      }
    }
    __syncthreads();
    if (tid < 192) {
      const int row  = tid >> 1;         // 0..95
      const int half = tid & 1;          // m half
      const int col  = nb0 - 2 * HID + row;
      const int h = col >> 6, d = col & 63;
      const int bb = mb0 >> 11;
      const int s0 = (mb0 & (SEQ - 1)) + half * 64;
      short* op = Vt + ((size_t)(bb * NHEAD + h) * HD + d) * SEQ + s0;
#pragma unroll
      for (int j = 0; j < 8; ++j)
        *(bf16x8*)(op + 8 * j) = *(const bf16x8*)&Tv[row][half * 64 + 8 * j];
    }
  }
}

// ---------------------------------------------------------------------------
// Flash attention (byte-identical to round 18 — verified 62 us steady-state).
// ---------------------------------------------------------------------------
__global__ __launch_bounds__(256, 3) void attn_fwd(
    const short* __restrict__ Qb, const short* __restrict__ Kb,
    const short* __restrict__ Vt, const float* __restrict__ mask2,
    float* __restrict__ out)
{
  __shared__ __align__(16) short KA[2][64][64];      // swizzled slots
  __shared__ __align__(16) short VA[2][64][64];      // swizzled slots
  __shared__ __align__(16) short PA[4][32][72];      // per-wave P [q][kv]

  const int tid  = threadIdx.x;
  const int w    = tid >> 6;         // wave 0..3
  const int pair = w >> 1;           // kv half
  const int pw   = w & 1;            // q half
  const int l    = tid & 63;
  const int r5   = l & 31;
  const int hi   = l >> 5;

  // XCD-locality remap: 768 blocks = 8 XCDs x (3 bh x 32 qblk)
  const int bid  = blockIdx.x;
  const int xcd  = bid & 7;
  const int slot = bid >> 3;         // 0..95
  const int bh   = xcd * 3 + (slot >> 5);
  const int qblk = slot & 31;

  const int b    = bh / 12;
  const int hh   = bh - b * 12;
  const int q0   = qblk * 64 + pw * 32;
  const int kb   = pair * 1024;      // kv base for this pair

  const short* __restrict__ Qh  = Qb + (size_t)bh * SEQ * HD;
  const short* __restrict__ Kh  = Kb + (size_t)bh * SEQ * HD;
  const short* __restrict__ Vth = Vt + (size_t)bh * HD * SEQ;
  const float* __restrict__ mb2 = mask2 + (size_t)b * SEQ;

  // Q fragments (B-operand): col q = r5, k(d) = 16j + 8hi + i
  bf16x8 qf[4];
#pragma unroll
  for (int j = 0; j < 4; ++j)
    qf[j] = *(const bf16x8*)(Qh + (size_t)(q0 + r5) * HD + 16 * j + 8 * hi);

  f32x16 o0 = (f32x16){0.f};
  f32x16 o1 = (f32x16){0.f};
  float lsum = 0.f;                  // per-lane partial; cross-half shfl deferred

  // pair-local staging: 128 threads cover K[64][64] + VT[64][64]
  const int ptid = tid & 127;
  const int sr = ptid >> 1;          // row 0..63
  const int sb = (ptid & 1) * 4;     // slot base (4 slots of 8 shorts)
  const short* __restrict__ Kp = Kh + (size_t)(kb + sr) * HD + sb * 8;
  const short* __restrict__ Vp = Vth + (size_t)sr * SEQ + kb + sb * 8;
  const int ssw = sr & 7;            // staging-row swizzle

  bf16x8 kst[4], vst[4];
#pragma unroll
  for (int j = 0; j < 4; ++j) {
    kst[j] = *(const bf16x8*)(Kp + 8 * j);
    vst[j] = *(const bf16x8*)(Vp + 8 * j);
  }
#pragma unroll
  for (int j = 0; j < 4; ++j) {
    *(bf16x8*)&KA[pair][sr][((sb + j) ^ ssw) * 8] = kst[j];
    *(bf16x8*)&VA[pair][sr][((sb + j) ^ ssw) * 8] = vst[j];
  }

  const int rsw = r5 & 7;            // read-row swizzle

  for (int t = 0; t < 16; ++t) {
    const int kv0 = kb + t * 64;
    __syncthreads();   // (1) staged writes of tile t visible

    // issue next tile's global loads (wrap within this pair's half)
    const size_t kvn = (size_t)(((t + 1) & 15) * 64);
#pragma unroll
    for (int j = 0; j < 4; ++j) {
      kst[j] = *(const bf16x8*)(Kp + kvn * HD + 8 * j);
      vst[j] = *(const bf16x8*)(Vp + kvn + 8 * j);
    }

    // S^T = K * Q^T : 2 kv-subtiles x 4 chained (d) 32x32x16 MFMAs
    f32x16 st0 = (f32x16){0.f};
    f32x16 st1 = (f32x16){0.f};
    __builtin_amdgcn_s_setprio(1);
#pragma unroll
    for (int j = 0; j < 4; ++j) {
      const int co = ((2 * j + hi) ^ rsw) * 8;
      bf16x8 ka0 = *(const bf16x8*)&KA[pair][r5][co];
      bf16x8 ka1 = *(const bf16x8*)&KA[pair][32 + r5][co];
      st0 = __builtin_amdgcn_mfma_f32_32x32x16_bf16(ka0, qf[j], st0, 0, 0, 0);
      st1 = __builtin_amdgcn_mfma_f32_32x32x16_bf16(ka1, qf[j], st1, 0, 0, 0);
    }
    __builtin_amdgcn_s_setprio(0);

    // fixed-max softmax: p = exp2(st*C1 + mask2[kv]) (mask2 pre-shifted -16)
    float p[2][16];
#pragma unroll
    for (int t2 = 0; t2 < 4; ++t2) {
      f32x4 mv0 = *(const f32x4*)&mb2[kv0 + 8 * t2 + 4 * hi];
      f32x4 mv1 = *(const f32x4*)&mb2[kv0 + 32 + 8 * t2 + 4 * hi];
#pragma unroll
      for (int e = 0; e < 4; ++e) {
        p[0][4 * t2 + e] = fexp2(st0[4 * t2 + e] * C1 + mv0[e]);
        p[1][4 * t2 + e] = fexp2(st1[4 * t2 + e] * C1 + mv1[e]);
      }
    }

    // pack P -> bf16 -> wave-private LDS FIRST (write latency hides under tree)
#pragma unroll
    for (int s2 = 0; s2 < 2; ++s2)
#pragma unroll
      for (int t2 = 0; t2 < 4; ++t2) {
        unsigned int u0, u1;
        asm("v_cvt_pk_bf16_f32 %0, %1, %2"
            : "=v"(u0) : "v"(p[s2][4 * t2 + 0]), "v"(p[s2][4 * t2 + 1]));
        asm("v_cvt_pk_bf16_f32 %0, %1, %2"
            : "=v"(u1) : "v"(p[s2][4 * t2 + 2]), "v"(p[s2][4 * t2 + 3]));
        uint2 uv; uv.x = u0; uv.y = u1;
        *(uint2*)&PA[w][r5][32 * s2 + 8 * t2 + 4 * hi] = uv;
      }

    // per-lane sum tree (cross-half shfl deferred to after the loop)
    float sm[8];
#pragma unroll
    for (int i = 0; i < 8; ++i)
      sm[i] = (p[0][2 * i] + p[0][2 * i + 1]) + (p[1][2 * i] + p[1][2 * i + 1]);
    lsum += ((sm[0] + sm[1]) + (sm[2] + sm[3])) + ((sm[4] + sm[5]) + (sm[6] + sm[7]));

    bf16x8 pf[4];
#pragma unroll
    for (int j = 0; j < 4; ++j)
      pf[j] = *(const bf16x8*)&PA[w][r5][16 * j + 8 * hi];

    // O^T += V^T * P^T
    __builtin_amdgcn_s_setprio(1);
#pragma unroll
    for (int j = 0; j < 4; ++j) {
      const int co = ((2 * j + hi) ^ rsw) * 8;
      bf16x8 va0 = *(const bf16x8*)&VA[pair][r5][co];
      bf16x8 va1 = *(const bf16x8*)&VA[pair][32 + r5][co];
      o0 = __builtin_amdgcn_mfma_f32_32x32x16_bf16(va0, pf[j], o0, 0, 0, 0);
      o1 = __builtin_amdgcn_mfma_f32_32x32x16_bf16(va1, pf[j], o1, 0, 0, 0);
    }
    __builtin_amdgcn_s_setprio(0);

    __syncthreads();   // (2) all reads of tile t done -> safe to overwrite
#pragma unroll
    for (int j = 0; j < 4; ++j) {
      *(bf16x8*)&KA[pair][sr][((sb + j) ^ ssw) * 8] = kst[j];
      *(bf16x8*)&VA[pair][sr][((sb + j) ^ ssw) * 8] = vst[j];
    }
  }

  // deferred cross-half reduce
  const float l_run = lsum + __shfl_xor(lsum, 32, 64);

  // ---- cross-pair merge: waves 2,3 publish (l,O); waves 0,1 combine ----
  __syncthreads();
  float* Os = (float*)&KA[0][0][0];   // [2][32][64] f32 = 16384 B, fits KA
  float* ML = (float*)&PA[0][0][0];   // [2][32] f32 in dead PA region

  if (w >= 2) {
    const int wv = w - 2;
    float* Or = Os + (size_t)(wv * 32 + r5) * 64;
#pragma unroll
    for (int t2 = 0; t2 < 4; ++t2) {
      f32x4 v0, v1;
#pragma unroll
      for (int e = 0; e < 4; ++e) { v0[e] = o0[4 * t2 + e]; v1[e] = o1[4 * t2 + e]; }
      *(f32x4*)&Or[8 * t2 + 4 * hi]      = v0;
      *(f32x4*)&Or[32 + 8 * t2 + 4 * hi] = v1;
    }
    if (hi == 0) ML[wv * 32 + r5] = l_run;
  }
  __syncthreads();
  if (w < 2) {
    const float lo  = ML[w * 32 + r5];
    const float inv = 1.f / (l_run + lo);
    const float* Or = Os + (size_t)(w * 32 + r5) * 64;
    float* ob = out + (size_t)(b * SEQ + q0 + r5) * HID + hh * HD;
#pragma unroll
    for (int t2 = 0; t2 < 4; ++t2) {
      f32x4 po = *(const f32x4*)&Or[8 * t2 + 4 * hi];
      f32x4 p1 = *(const f32x4*)&Or[32 + 8 * t2 + 4 * hi];
      f32x4 v0, v1;
#pragma unroll
      for (int e = 0; e < 4; ++e) {
        v0[e] = (o0[4 * t2 + e] + po[e]) * inv;
        v1[e] = (o1[4 * t2 + e] + p1[e]) * inv;
      }
      *(f32x4*)&ob[8 * t2 + 4 * hi]      = v0;
      *(f32x4*)&ob[32 + 8 * t2 + 4 * hi] = v1;
    }
  }
}

// ---------------------------------------------------------------------------
extern "C" void kernel_launch(void* const* d_in, const int* in_sizes, int n_in,
                              void* d_out, int out_size, void* d_ws, size_t ws_size,
                              hipStream_t stream) {
  const float* X    = (const float*)d_in[0];
  const float* mask = (const float*)d_in[1];
  const float* Wq   = (const float*)d_in[2];
  const float* bq   = (const float*)d_in[3];
  const float* Wk   = (const float*)d_in[4];
  const float* bk   = (const float*)d_in[5];
  const float* Wv   = (const float*)d_in[6];
  const float* bv   = (const float*)d_in[7];
  float* out = (float*)d_out;

  short* Qb = (short*)d_ws;
  short* Kb = Qb + PH;
  short* Vt = Kb + PH;                 // V stored transposed [bh][d][s]
  short* Xb = Vt + PH;
  short* Wt = Xb + XEL;
  float* mask2 = (float*)(Wt + (size_t)3 * HID * HID);

  prep<<<dim3(1201), 256, 0, stream>>>(X, Wq, Wk, Wv, mask, Xb, Wt, mask2);
  qkv_gemm<<<dim3(768), 256, 0, stream>>>(Xb, Wt, bq, bk, bv, Qb, Kb, Vt);
  attn_fwd<<<dim3(768), 256, 0, stream>>>(Qb, Kb, Vt, mask2, out);
}

// Round 20
// 80.546 us; speedup vs baseline: 2.2727x; 1.0254x over previous
//
#include <hip/hip_runtime.h>

#define HID 768
#define NHEAD 12
#define HD 64
#define SEQ 2048
#define BATCH 2
#define PH (BATCH * NHEAD * SEQ * HD)   // 3,145,728 elements per Q/K/V plane
#define XEL (BATCH * SEQ * HID)
#define LOG2E 1.4426950408889634f
#define C1 (0.125f * LOG2E)             // QK scale folded with log2e
#define FMAX2 16.0f                     // fixed softmax max (log2 domain)

typedef __attribute__((ext_vector_type(8))) short bf16x8;
typedef __attribute__((ext_vector_type(4))) short bf16x4;
typedef __attribute__((ext_vector_type(4))) float f32x4;
typedef __attribute__((ext_vector_type(16))) float f32x16;

static __device__ __forceinline__ short f2b(float f) {
  unsigned int u = __builtin_bit_cast(unsigned int, f);
  unsigned int r = (u + 0x7fffu + ((u >> 16) & 1u)) >> 16;
  return (short)(unsigned short)r;
}

static __device__ __forceinline__ float fexp2(float x) {
  float r; asm("v_exp_f32 %0, %1" : "=v"(r) : "v"(x)); return r;
}

// ---------------------------------------------------------------------------
// Prep (byte-identical to round 19)
// ---------------------------------------------------------------------------
__global__ __launch_bounds__(256) void prep(
    const float* __restrict__ X,
    const float* __restrict__ Wq, const float* __restrict__ Wk,
    const float* __restrict__ Wv, const float* __restrict__ mask,
    short* __restrict__ Xb, short* __restrict__ Wt, float* __restrict__ mask2)
{
  __shared__ short T[64][65];
  const int t = threadIdx.x;
  const int blk = blockIdx.x;
  if (blk < 768) {
    const size_t base = (size_t)blk * 4096 + t * 16;
    f32x4 a0 = *(const f32x4*)(X + base);
    f32x4 a1 = *(const f32x4*)(X + base + 4);
    f32x4 a2 = *(const f32x4*)(X + base + 8);
    f32x4 a3 = *(const f32x4*)(X + base + 12);
    bf16x8 o0, o1;
#pragma unroll
    for (int i = 0; i < 4; ++i) {
      o0[i] = f2b(a0[i]); o0[4 + i] = f2b(a1[i]);
      o1[i] = f2b(a2[i]); o1[4 + i] = f2b(a3[i]);
    }
    *(bf16x8*)(Xb + base) = o0;
    *(bf16x8*)(Xb + base + 8) = o1;
  } else if (blk < 1200) {
    const int wb   = blk - 768;
    const int mat  = wb / 144;
    const int tile = wb - mat * 144;
    const int r0 = (tile / 12) * 64;
    const int c0 = (tile % 12) * 64;
    const float* __restrict__ W = (mat == 0) ? Wq : (mat == 1 ? Wk : Wv);
#pragma unroll
    for (int i = 0; i < 4; ++i) {
      const int r = (t >> 4) + 16 * i;
      const int c = (t & 15) * 4;
      f32x4 v = *(const f32x4*)(W + (size_t)(r0 + r) * HID + c0 + c);
      T[r][c + 0] = f2b(v[0]); T[r][c + 1] = f2b(v[1]);
      T[r][c + 2] = f2b(v[2]); T[r][c + 3] = f2b(v[3]);
    }
    __syncthreads();
    const int cr = t >> 2;
    const int ck = (t & 3) * 16;
    bf16x8 u0, u1;
#pragma unroll
    for (int j = 0; j < 8; ++j) { u0[j] = T[ck + j][cr]; u1[j] = T[ck + 8 + j][cr]; }
    short* orow = Wt + (size_t)(mat * HID + c0 + cr) * HID + r0 + ck;
    *(bf16x8*)orow = u0;
    *(bf16x8*)(orow + 8) = u1;
  } else {
#pragma unroll
    for (int i = 0; i < 4; ++i) {
      const int idx = (t * 4 + i * 1024);
      f32x4 v = *(const f32x4*)(mask + idx);
      v = v * LOG2E - FMAX2;
      *(f32x4*)(mask2 + idx) = v;
    }
  }
}

// ---------------------------------------------------------------------------
// Fused QKV GEMM v2 (byte-identical to round 19): 128x96 tiles, grid 768.
// ---------------------------------------------------------------------------
__global__ __launch_bounds__(256, 3) void qkv_gemm(
    const short* __restrict__ Xb, const short* __restrict__ Wt,
    const float* __restrict__ bq, const float* __restrict__ bk,
    const float* __restrict__ bv,
    short* __restrict__ Qb, short* __restrict__ Kb, short* __restrict__ Vt)
{
  __shared__ __align__(16) short SM[128 * 64 + 96 * 64];
  short (*A_lds)[64] = (short(*)[64])SM;
  short (*B_lds)[64] = (short(*)[64])(SM + 128 * 64);
  short (*Tv)[132]   = (short(*)[132])SM;

  const int tid = threadIdx.x;
  const int w  = tid >> 6;
  const int l  = tid & 63;
  const int lr = l & 15;
  const int g  = l >> 4;
  const int wm = w >> 1;
  const int wn = w & 1;

  const int raw = blockIdx.x;
  const int swz = (raw & 7) * 96 + (raw >> 3);
  const int by  = swz / 24;
  const int bx  = swz - by * 24;
  const int mb0 = by * 128;
  const int nb0 = bx * 96;

  const int lrow8 = l >> 3;
  const int lslot = (l & 7) ^ lrow8;
  const short* __restrict__ pA = Xb + (size_t)(mb0 + w * 32 + lrow8) * HID + lslot * 8;
  const short* __restrict__ pB = Wt + (size_t)(nb0 + w * 24 + lrow8) * HID + lslot * 8;

  f32x4 acc[4][3];
#pragma unroll
  for (int mi = 0; mi < 4; ++mi)
#pragma unroll
    for (int ni = 0; ni < 3; ++ni) acc[mi][ni] = (f32x4){0.f, 0.f, 0.f, 0.f};

  const int rsw = (lr & 7) << 3;

  for (int ks = 0; ks < HID / 64; ++ks) {
    const int k0 = ks * 64;
    __syncthreads();
#pragma unroll
    for (int i = 0; i < 4; ++i)
      __builtin_amdgcn_global_load_lds(
          (const void*)(pA + k0 + i * 8 * HID), (void*)&A_lds[w * 32 + i * 8][0], 16, 0, 0);
#pragma unroll
    for (int i = 0; i < 3; ++i)
      __builtin_amdgcn_global_load_lds(
          (const void*)(pB + k0 + i * 8 * HID), (void*)&B_lds[w * 24 + i * 8][0], 16, 0, 0);
    __syncthreads();

#pragma unroll
    for (int h = 0; h < 2; ++h) {
      const int coff = (((h << 2) | g) << 3) ^ rsw;
      bf16x8 a[4], b[3];
#pragma unroll
      for (int i = 0; i < 4; ++i)
        a[i] = *(const bf16x8*)&A_lds[wm * 64 + 16 * i + lr][coff];
#pragma unroll
      for (int i = 0; i < 3; ++i)
        b[i] = *(const bf16x8*)&B_lds[wn * 48 + 16 * i + lr][coff];
#pragma unroll
      for (int mi = 0; mi < 4; ++mi)
#pragma unroll
        for (int ni = 0; ni < 3; ++ni)
          acc[mi][ni] = __builtin_amdgcn_mfma_f32_16x16x32_bf16(a[mi], b[ni], acc[mi][ni], 0, 0, 0);
    }
  }

  const int mat  = bx >> 3;
  const int n0   = nb0 + wn * 48;
  const int m0   = mb0 + wm * 64;
  const int colb = n0 - mat * HID;

  if (mat < 2) {
    const float* __restrict__ bias = (mat == 0) ? bq : bk;
    short* __restrict__ Out        = (mat == 0) ? Qb : Kb;
#pragma unroll
    for (int ni = 0; ni < 3; ++ni) {
      const int col = colb + 16 * ni + lr;
      const int h = col >> 6, d = col & 63;
      const float bias_v = bias[col];
#pragma unroll
      for (int mi = 0; mi < 4; ++mi) {
        const int mbase = m0 + 16 * mi + 4 * g;
#pragma unroll
        for (int r = 0; r < 4; ++r) {
          const int m = mbase + r;
          const int bb = m >> 11;
          const int s  = m & (SEQ - 1);
          Out[((size_t)(bb * NHEAD + h) * SEQ + s) * HD + d] = f2b(acc[mi][ni][r] + bias_v);
        }
      }
    }
  } else {
    __syncthreads();
#pragma unroll
    for (int ni = 0; ni < 3; ++ni) {
      const int col = colb + 16 * ni + lr;
      const float bias_v = bv[col];
      const int rowl = wn * 48 + 16 * ni + lr;
#pragma unroll
      for (int mi = 0; mi < 4; ++mi) {
        bf16x4 pk;
#pragma unroll
        for (int r = 0; r < 4; ++r) pk[r] = f2b(acc[mi][ni][r] + bias_v);
        *(bf16x4*)&Tv[rowl][wm * 64 + 16 * mi + 4 * g] = pk;
      }
    }
    __syncthreads();
    if (tid < 192) {
      const int row  = tid >> 1;
      const int half = tid & 1;
      const int col  = nb0 - 2 * HID + row;
      const int h = col >> 6, d = col & 63;
      const int bb = mb0 >> 11;
      const int s0 = (mb0 & (SEQ - 1)) + half * 64;
      short* op = Vt + ((size_t)(bb * NHEAD + h) * HD + d) * SEQ + s0;
#pragma unroll
      for (int j = 0; j < 8; ++j)
        *(bf16x8*)(op + 8 * j) = *(const bf16x8*)&Tv[row][half * 64 + 8 * j];
    }
  }
}

// ---------------------------------------------------------------------------
// Flash attention v11: round-19 structure with the P LDS roundtrip replaced
// by in-register assembly via v_permlane32_swap (vdst-HIGH <-> vsrc-LOW,
// direction deduced from round-8 falsification):
//   A = cvt_pk(own t2=2j words), B = cvt_pk(own t2=2j+1 words)
//   swap(A0,B0); swap(A1,B1)  ->  frag = {A0', A1', B0', B1'}
// Byte-equivalent to the verified PA path. PA removed from loop; LDS 33 KB.
// ---------------------------------------------------------------------------
__global__ __launch_bounds__(256, 3) void attn_fwd(
    const short* __restrict__ Qb, const short* __restrict__ Kb,
    const short* __restrict__ Vt, const float* __restrict__ mask2,
    float* __restrict__ out)
{
  __shared__ __align__(16) short KA[2][64][64];      // swizzled slots
  __shared__ __align__(16) short VA[2][64][64];      // swizzled slots
  __shared__ float ML[64];                           // merge l exchange

  const int tid  = threadIdx.x;
  const int w    = tid >> 6;         // wave 0..3
  const int pair = w >> 1;           // kv half
  const int pw   = w & 1;            // q half
  const int l    = tid & 63;
  const int r5   = l & 31;
  const int hi   = l >> 5;

  // XCD-locality remap: 768 blocks = 8 XCDs x (3 bh x 32 qblk)
  const int bid  = blockIdx.x;
  const int xcd  = bid & 7;
  const int slot = bid >> 3;
  const int bh   = xcd * 3 + (slot >> 5);
  const int qblk = slot & 31;

  const int b    = bh / 12;
  const int hh   = bh - b * 12;
  const int q0   = qblk * 64 + pw * 32;
  const int kb   = pair * 1024;

  const short* __restrict__ Qh  = Qb + (size_t)bh * SEQ * HD;
  const short* __restrict__ Kh  = Kb + (size_t)bh * SEQ * HD;
  const short* __restrict__ Vth = Vt + (size_t)bh * HD * SEQ;
  const float* __restrict__ mb2 = mask2 + (size_t)b * SEQ;

  bf16x8 qf[4];
#pragma unroll
  for (int j = 0; j < 4; ++j)
    qf[j] = *(const bf16x8*)(Qh + (size_t)(q0 + r5) * HD + 16 * j + 8 * hi);

  f32x16 o0 = (f32x16){0.f};
  f32x16 o1 = (f32x16){0.f};
  float lsum = 0.f;

  const int ptid = tid & 127;
  const int sr = ptid >> 1;
  const int sb = (ptid & 1) * 4;
  const short* __restrict__ Kp = Kh + (size_t)(kb + sr) * HD + sb * 8;
  const short* __restrict__ Vp = Vth + (size_t)sr * SEQ + kb + sb * 8;
  const int ssw = sr & 7;

  bf16x8 kst[4], vst[4];
#pragma unroll
  for (int j = 0; j < 4; ++j) {
    kst[j] = *(const bf16x8*)(Kp + 8 * j);
    vst[j] = *(const bf16x8*)(Vp + 8 * j);
  }
#pragma unroll
  for (int j = 0; j < 4; ++j) {
    *(bf16x8*)&KA[pair][sr][((sb + j) ^ ssw) * 8] = kst[j];
    *(bf16x8*)&VA[pair][sr][((sb + j) ^ ssw) * 8] = vst[j];
  }

  const int rsw = r5 & 7;

  for (int t = 0; t < 16; ++t) {
    const int kv0 = kb + t * 64;
    __syncthreads();   // (1) staged writes of tile t visible

    const size_t kvn = (size_t)(((t + 1) & 15) * 64);
#pragma unroll
    for (int j = 0; j < 4; ++j) {
      kst[j] = *(const bf16x8*)(Kp + kvn * HD + 8 * j);
      vst[j] = *(const bf16x8*)(Vp + kvn + 8 * j);
    }

    // S^T = K * Q^T
    f32x16 st0 = (f32x16){0.f};
    f32x16 st1 = (f32x16){0.f};
    __builtin_amdgcn_s_setprio(1);
#pragma unroll
    for (int j = 0; j < 4; ++j) {
      const int co = ((2 * j + hi) ^ rsw) * 8;
      bf16x8 ka0 = *(const bf16x8*)&KA[pair][r5][co];
      bf16x8 ka1 = *(const bf16x8*)&KA[pair][32 + r5][co];
      st0 = __builtin_amdgcn_mfma_f32_32x32x16_bf16(ka0, qf[j], st0, 0, 0, 0);
      st1 = __builtin_amdgcn_mfma_f32_32x32x16_bf16(ka1, qf[j], st1, 0, 0, 0);
    }
    __builtin_amdgcn_s_setprio(0);

    // fixed-max softmax
    float p[2][16];
#pragma unroll
    for (int t2 = 0; t2 < 4; ++t2) {
      f32x4 mv0 = *(const f32x4*)&mb2[kv0 + 8 * t2 + 4 * hi];
      f32x4 mv1 = *(const f32x4*)&mb2[kv0 + 32 + 8 * t2 + 4 * hi];
#pragma unroll
      for (int e = 0; e < 4; ++e) {
        p[0][4 * t2 + e] = fexp2(st0[4 * t2 + e] * C1 + mv0[e]);
        p[1][4 * t2 + e] = fexp2(st1[4 * t2 + e] * C1 + mv1[e]);
      }
    }

    // pack P -> bf16 words: wq[s2][t2][u] covers kv = 32s2 + 8t2 + 4hi + {2u,2u+1}
    unsigned int wq[2][4][2];
#pragma unroll
    for (int s2 = 0; s2 < 2; ++s2)
#pragma unroll
      for (int t2 = 0; t2 < 4; ++t2) {
        asm("v_cvt_pk_bf16_f32 %0, %1, %2"
            : "=v"(wq[s2][t2][0]) : "v"(p[s2][4 * t2 + 0]), "v"(p[s2][4 * t2 + 1]));
        asm("v_cvt_pk_bf16_f32 %0, %1, %2"
            : "=v"(wq[s2][t2][1]) : "v"(p[s2][4 * t2 + 2]), "v"(p[s2][4 * t2 + 3]));
      }

    // assemble PV B-frags in-register: swap(A=t2-even, B=t2-odd);
    // vdst-high <-> vsrc-low  =>  frag = {A0', A1', B0', B1'}
    bf16x8 pf[4];
#pragma unroll
    for (int s2 = 0; s2 < 2; ++s2)
#pragma unroll
      for (int jl = 0; jl < 2; ++jl) {
        unsigned int a0 = wq[s2][2 * jl][0], b0 = wq[s2][2 * jl + 1][0];
        unsigned int a1 = wq[s2][2 * jl][1], b1 = wq[s2][2 * jl + 1][1];
        asm("v_permlane32_swap_b32 %0, %1" : "+v"(a0), "+v"(b0));
        asm("v_permlane32_swap_b32 %0, %1" : "+v"(a1), "+v"(b1));
        uint4 fw; fw.x = a0; fw.y = a1; fw.z = b0; fw.w = b1;
        pf[2 * s2 + jl] = __builtin_bit_cast(bf16x8, fw);
      }

    // per-lane sum tree (cross-half shfl deferred)
    float sm[8];
#pragma unroll
    for (int i = 0; i < 8; ++i)
      sm[i] = (p[0][2 * i] + p[0][2 * i + 1]) + (p[1][2 * i] + p[1][2 * i + 1]);
    lsum += ((sm[0] + sm[1]) + (sm[2] + sm[3])) + ((sm[4] + sm[5]) + (sm[6] + sm[7]));

    // O^T += V^T * P^T
    __builtin_amdgcn_s_setprio(1);
#pragma unroll
    for (int j = 0; j < 4; ++j) {
      const int co = ((2 * j + hi) ^ rsw) * 8;
      bf16x8 va0 = *(const bf16x8*)&VA[pair][r5][co];
      bf16x8 va1 = *(const bf16x8*)&VA[pair][32 + r5][co];
      o0 = __builtin_amdgcn_mfma_f32_32x32x16_bf16(va0, pf[j], o0, 0, 0, 0);
      o1 = __builtin_amdgcn_mfma_f32_32x32x16_bf16(va1, pf[j], o1, 0, 0, 0);
    }
    __builtin_amdgcn_s_setprio(0);

    __syncthreads();   // (2) all reads of tile t done -> safe to overwrite
#pragma unroll
    for (int j = 0; j < 4; ++j) {
      *(bf16x8*)&KA[pair][sr][((sb + j) ^ ssw) * 8] = kst[j];
      *(bf16x8*)&VA[pair][sr][((sb + j) ^ ssw) * 8] = vst[j];
    }
  }

  // deferred cross-half reduce
  const float l_run = lsum + __shfl_xor(lsum, 32, 64);

  // ---- cross-pair merge: waves 2,3 publish (l,O); waves 0,1 combine ----
  __syncthreads();
  float* Os = (float*)&KA[0][0][0];   // [2][32][64] f32 = 16384 B, fits KA

  if (w >= 2) {
    const int wv = w - 2;
    float* Or = Os + (size_t)(wv * 32 + r5) * 64;
#pragma unroll
    for (int t2 = 0; t2 < 4; ++t2) {
      f32x4 v0, v1;
#pragma unroll
      for (int e = 0; e < 4; ++e) { v0[e] = o0[4 * t2 + e]; v1[e] = o1[4 * t2 + e]; }
      *(f32x4*)&Or[8 * t2 + 4 * hi]      = v0;
      *(f32x4*)&Or[32 + 8 * t2 + 4 * hi] = v1;
    }
    if (hi == 0) ML[wv * 32 + r5] = l_run;
  }
  __syncthreads();
  if (w < 2) {
    const float lo  = ML[w * 32 + r5];
    const float inv = 1.f / (l_run + lo);
    const float* Or = Os + (size_t)(w * 32 + r5) * 64;
    float* ob = out + (size_t)(b * SEQ + q0 + r5) * HID + hh * HD;
#pragma unroll
    for (int t2 = 0; t2 < 4; ++t2) {
      f32x4 po = *(const f32x4*)&Or[8 * t2 + 4 * hi];
      f32x4 p1 = *(const f32x4*)&Or[32 + 8 * t2 + 4 * hi];
      f32x4 v0, v1;
#pragma unroll
      for (int e = 0; e < 4; ++e) {
        v0[e] = (o0[4 * t2 + e] + po[e]) * inv;
        v1[e] = (o1[4 * t2 + e] + p1[e]) * inv;
      }
      *(f32x4*)&ob[8 * t2 + 4 * hi]      = v0;
      *(f32x4*)&ob[32 + 8 * t2 + 4 * hi] = v1;
    }
  }
}

// ---------------------------------------------------------------------------
extern "C" void kernel_launch(void* const* d_in, const int* in_sizes, int n_in,
                              void* d_out, int out_size, void* d_ws, size_t ws_size,
                              hipStream_t stream) {
  const float* X    = (const float*)d_in[0];
  const float* mask = (const float*)d_in[1];
  const float* Wq   = (const float*)d_in[2];
  const float* bq   = (const float*)d_in[3];
  const float* Wk   = (const float*)d_in[4];
  const float* bk   = (const float*)d_in[5];
  const float* Wv   = (const float*)d_in[6];
  const float* bv   = (const float*)d_in[7];
  float* out = (float*)d_out;

  short* Qb = (short*)d_ws;
  short* Kb = Qb + PH;
  short* Vt = Kb + PH;                 // V stored transposed [bh][d][s]
  short* Xb = Vt + PH;
  short* Wt = Xb + XEL;
  float* mask2 = (float*)(Wt + (size_t)3 * HID * HID);

  prep<<<dim3(1201), 256, 0, stream>>>(X, Wq, Wk, Wv, mask, Xb, Wt, mask2);
  qkv_gemm<<<dim3(768), 256, 0, stream>>>(Xb, Wt, bq, bk, bv, Qb, Kb, Vt);
  attn_fwd<<<dim3(768), 256, 0, stream>>>(Qb, Kb, Vt, mask2, out);
}

// Round 21
// 73.738 us; speedup vs baseline: 2.4826x; 1.0923x over previous
//
#include <hip/hip_runtime.h>

#define HID 768
#define NHEAD 12
#define HD 64
#define SEQ 2048
#define BATCH 2
#define PH (BATCH * NHEAD * SEQ * HD)   // 3,145,728 elements per Q/K/V plane
#define XEL (BATCH * SEQ * HID)
#define LOG2E 1.4426950408889634f
#define C1 (0.125f * LOG2E)             // QK scale folded with log2e
#define FMAX2 16.0f                     // fixed softmax max (log2 domain)

typedef __attribute__((ext_vector_type(8))) short bf16x8;
typedef __attribute__((ext_vector_type(4))) short bf16x4;
typedef __attribute__((ext_vector_type(4))) float f32x4;
typedef __attribute__((ext_vector_type(16))) float f32x16;

static __device__ __forceinline__ short f2b(float f) {
  unsigned int u = __builtin_bit_cast(unsigned int, f);
  unsigned int r = (u + 0x7fffu + ((u >> 16) & 1u)) >> 16;
  return (short)(unsigned short)r;
}

static __device__ __forceinline__ float fexp2(float x) {
  float r; asm("v_exp_f32 %0, %1" : "=v"(r) : "v"(x)); return r;
}

// ---------------------------------------------------------------------------
// Prep (byte-identical to round 20)
// ---------------------------------------------------------------------------
__global__ __launch_bounds__(256) void prep(
    const float* __restrict__ X,
    const float* __restrict__ Wq, const float* __restrict__ Wk,
    const float* __restrict__ Wv, const float* __restrict__ mask,
    short* __restrict__ Xb, short* __restrict__ Wt, float* __restrict__ mask2)
{
  __shared__ short T[64][65];
  const int t = threadIdx.x;
  const int blk = blockIdx.x;
  if (blk < 768) {
    const size_t base = (size_t)blk * 4096 + t * 16;
    f32x4 a0 = *(const f32x4*)(X + base);
    f32x4 a1 = *(const f32x4*)(X + base + 4);
    f32x4 a2 = *(const f32x4*)(X + base + 8);
    f32x4 a3 = *(const f32x4*)(X + base + 12);
    bf16x8 o0, o1;
#pragma unroll
    for (int i = 0; i < 4; ++i) {
      o0[i] = f2b(a0[i]); o0[4 + i] = f2b(a1[i]);
      o1[i] = f2b(a2[i]); o1[4 + i] = f2b(a3[i]);
    }
    *(bf16x8*)(Xb + base) = o0;
    *(bf16x8*)(Xb + base + 8) = o1;
  } else if (blk < 1200) {
    const int wb   = blk - 768;
    const int mat  = wb / 144;
    const int tile = wb - mat * 144;
    const int r0 = (tile / 12) * 64;
    const int c0 = (tile % 12) * 64;
    const float* __restrict__ W = (mat == 0) ? Wq : (mat == 1 ? Wk : Wv);
#pragma unroll
    for (int i = 0; i < 4; ++i) {
      const int r = (t >> 4) + 16 * i;
      const int c = (t & 15) * 4;
      f32x4 v = *(const f32x4*)(W + (size_t)(r0 + r) * HID + c0 + c);
      T[r][c + 0] = f2b(v[0]); T[r][c + 1] = f2b(v[1]);
      T[r][c + 2] = f2b(v[2]); T[r][c + 3] = f2b(v[3]);
    }
    __syncthreads();
    const int cr = t >> 2;
    const int ck = (t & 3) * 16;
    bf16x8 u0, u1;
#pragma unroll
    for (int j = 0; j < 8; ++j) { u0[j] = T[ck + j][cr]; u1[j] = T[ck + 8 + j][cr]; }
    short* orow = Wt + (size_t)(mat * HID + c0 + cr) * HID + r0 + ck;
    *(bf16x8*)orow = u0;
    *(bf16x8*)(orow + 8) = u1;
  } else {
#pragma unroll
    for (int i = 0; i < 4; ++i) {
      const int idx = (t * 4 + i * 1024);
      f32x4 v = *(const f32x4*)(mask + idx);
      v = v * LOG2E - FMAX2;
      *(f32x4*)(mask2 + idx) = v;
    }
  }
}

// ---------------------------------------------------------------------------
// Fused QKV GEMM v2 (byte-identical to round 20): 128x96 tiles, grid 768.
// ---------------------------------------------------------------------------
__global__ __launch_bounds__(256, 3) void qkv_gemm(
    const short* __restrict__ Xb, const short* __restrict__ Wt,
    const float* __restrict__ bq, const float* __restrict__ bk,
    const float* __restrict__ bv,
    short* __restrict__ Qb, short* __restrict__ Kb, short* __restrict__ Vt)
{
  __shared__ __align__(16) short SM[128 * 64 + 96 * 64];
  short (*A_lds)[64] = (short(*)[64])SM;
  short (*B_lds)[64] = (short(*)[64])(SM + 128 * 64);
  short (*Tv)[132]   = (short(*)[132])SM;

  const int tid = threadIdx.x;
  const int w  = tid >> 6;
  const int l  = tid & 63;
  const int lr = l & 15;
  const int g  = l >> 4;
  const int wm = w >> 1;
  const int wn = w & 1;

  const int raw = blockIdx.x;
  const int swz = (raw & 7) * 96 + (raw >> 3);
  const int by  = swz / 24;
  const int bx  = swz - by * 24;
  const int mb0 = by * 128;
  const int nb0 = bx * 96;

  const int lrow8 = l >> 3;
  const int lslot = (l & 7) ^ lrow8;
  const short* __restrict__ pA = Xb + (size_t)(mb0 + w * 32 + lrow8) * HID + lslot * 8;
  const short* __restrict__ pB = Wt + (size_t)(nb0 + w * 24 + lrow8) * HID + lslot * 8;

  f32x4 acc[4][3];
#pragma unroll
  for (int mi = 0; mi < 4; ++mi)
#pragma unroll
    for (int ni = 0; ni < 3; ++ni) acc[mi][ni] = (f32x4){0.f, 0.f, 0.f, 0.f};

  const int rsw = (lr & 7) << 3;

  for (int ks = 0; ks < HID / 64; ++ks) {
    const int k0 = ks * 64;
    __syncthreads();
#pragma unroll
    for (int i = 0; i < 4; ++i)
      __builtin_amdgcn_global_load_lds(
          (const void*)(pA + k0 + i * 8 * HID), (void*)&A_lds[w * 32 + i * 8][0], 16, 0, 0);
#pragma unroll
    for (int i = 0; i < 3; ++i)
      __builtin_amdgcn_global_load_lds(
          (const void*)(pB + k0 + i * 8 * HID), (void*)&B_lds[w * 24 + i * 8][0], 16, 0, 0);
    __syncthreads();

#pragma unroll
    for (int h = 0; h < 2; ++h) {
      const int coff = (((h << 2) | g) << 3) ^ rsw;
      bf16x8 a[4], b[3];
#pragma unroll
      for (int i = 0; i < 4; ++i)
        a[i] = *(const bf16x8*)&A_lds[wm * 64 + 16 * i + lr][coff];
#pragma unroll
      for (int i = 0; i < 3; ++i)
        b[i] = *(const bf16x8*)&B_lds[wn * 48 + 16 * i + lr][coff];
#pragma unroll
      for (int mi = 0; mi < 4; ++mi)
#pragma unroll
        for (int ni = 0; ni < 3; ++ni)
          acc[mi][ni] = __builtin_amdgcn_mfma_f32_16x16x32_bf16(a[mi], b[ni], acc[mi][ni], 0, 0, 0);
    }
  }

  const int mat  = bx >> 3;
  const int n0   = nb0 + wn * 48;
  const int m0   = mb0 + wm * 64;
  const int colb = n0 - mat * HID;

  if (mat < 2) {
    const float* __restrict__ bias = (mat == 0) ? bq : bk;
    short* __restrict__ Out        = (mat == 0) ? Qb : Kb;
#pragma unroll
    for (int ni = 0; ni < 3; ++ni) {
      const int col = colb + 16 * ni + lr;
      const int h = col >> 6, d = col & 63;
      const float bias_v = bias[col];
#pragma unroll
      for (int mi = 0; mi < 4; ++mi) {
        const int mbase = m0 + 16 * mi + 4 * g;
#pragma unroll
        for (int r = 0; r < 4; ++r) {
          const int m = mbase + r;
          const int bb = m >> 11;
          const int s  = m & (SEQ - 1);
          Out[((size_t)(bb * NHEAD + h) * SEQ + s) * HD + d] = f2b(acc[mi][ni][r] + bias_v);
        }
      }
    }
  } else {
    __syncthreads();
#pragma unroll
    for (int ni = 0; ni < 3; ++ni) {
      const int col = colb + 16 * ni + lr;
      const float bias_v = bv[col];
      const int rowl = wn * 48 + 16 * ni + lr;
#pragma unroll
      for (int mi = 0; mi < 4; ++mi) {
        bf16x4 pk;
#pragma unroll
        for (int r = 0; r < 4; ++r) pk[r] = f2b(acc[mi][ni][r] + bias_v);
        *(bf16x4*)&Tv[rowl][wm * 64 + 16 * mi + 4 * g] = pk;
      }
    }
    __syncthreads();
    if (tid < 192) {
      const int row  = tid >> 1;
      const int half = tid & 1;
      const int col  = nb0 - 2 * HID + row;
      const int h = col >> 6, d = col & 63;
      const int bb = mb0 >> 11;
      const int s0 = (mb0 & (SEQ - 1)) + half * 64;
      short* op = Vt + ((size_t)(bb * NHEAD + h) * HD + d) * SEQ + s0;
#pragma unroll
      for (int j = 0; j < 8; ++j)
        *(bf16x8*)(op + 8 * j) = *(const bf16x8*)&Tv[row][half * 64 + 8 * j];
    }
  }
}

// ---------------------------------------------------------------------------
// Flash attention v12: round-20 compute, staging loads made CONTIGUOUS.
// Lane geometry: row = l>>3, slot = l&7; each K-load instr = 1 KB contiguous
// (16 cache lines vs 64 before), V = 8 x 128B rows. Swizzle moved from the
// source address to the ds_write address; LDS CONTENT byte-identical:
//   KA[r][(s ^ (r&7))*8] = K[kv0+r][8s..8s+7]   (read side unchanged)
// ---------------------------------------------------------------------------
__global__ __launch_bounds__(256, 3) void attn_fwd(
    const short* __restrict__ Qb, const short* __restrict__ Kb,
    const short* __restrict__ Vt, const float* __restrict__ mask2,
    float* __restrict__ out)
{
  __shared__ __align__(16) short KA[2][64][64];      // swizzled slots
  __shared__ __align__(16) short VA[2][64][64];      // swizzled slots
  __shared__ float ML[64];                           // merge l exchange

  const int tid  = threadIdx.x;
  const int w    = tid >> 6;         // wave 0..3
  const int pair = w >> 1;           // kv half
  const int pw   = w & 1;            // q half
  const int l    = tid & 63;
  const int r5   = l & 31;
  const int hi   = l >> 5;

  // XCD-locality remap: 768 blocks = 8 XCDs x (3 bh x 32 qblk)
  const int bid  = blockIdx.x;
  const int xcd  = bid & 7;
  const int slot = bid >> 3;
  const int bh   = xcd * 3 + (slot >> 5);
  const int qblk = slot & 31;

  const int b    = bh / 12;
  const int hh   = bh - b * 12;
  const int q0   = qblk * 64 + pw * 32;
  const int kb   = pair * 1024;

  const short* __restrict__ Qh  = Qb + (size_t)bh * SEQ * HD;
  const short* __restrict__ Kh  = Kb + (size_t)bh * SEQ * HD;
  const short* __restrict__ Vth = Vt + (size_t)bh * HD * SEQ;
  const float* __restrict__ mb2 = mask2 + (size_t)b * SEQ;

  bf16x8 qf[4];
#pragma unroll
  for (int j = 0; j < 4; ++j)
    qf[j] = *(const bf16x8*)(Qh + (size_t)(q0 + r5) * HD + 16 * j + 8 * hi);

  f32x16 o0 = (f32x16){0.f};
  f32x16 o1 = (f32x16){0.f};
  float lsum = 0.f;

  // NEW staging geometry: wave pw of each pair covers rows [pw*32, pw*32+32).
  // Instr i covers 8 consecutive rows; lane l -> row lr8 = l>>3, slot ls8 = l&7.
  // K loads are contiguous 1 KB per instruction; V loads 8 x 128B rows.
  const int lr8 = l >> 3;            // 0..7 row within group
  const int ls8 = l & 7;             // straight slot (source)
  const int ssw2 = ls8 ^ lr8;        // ds_write slot: (slot ^ (row&7)), row&7==lr8
  const short* __restrict__ Kp = Kh + (size_t)(kb + pw * 32 + lr8) * HD + ls8 * 8;
  const short* __restrict__ Vp = Vth + (size_t)(pw * 32 + lr8) * SEQ + kb + ls8 * 8;
  const int rbase = pw * 32 + lr8;   // LDS row base for this lane

  bf16x8 kst[4], vst[4];
#pragma unroll
  for (int j = 0; j < 4; ++j) {
    kst[j] = *(const bf16x8*)(Kp + (size_t)(8 * j) * HD);
    vst[j] = *(const bf16x8*)(Vp + (size_t)(8 * j) * SEQ);
  }
#pragma unroll
  for (int j = 0; j < 4; ++j) {
    *(bf16x8*)&KA[pair][rbase + 8 * j][ssw2 * 8] = kst[j];
    *(bf16x8*)&VA[pair][rbase + 8 * j][ssw2 * 8] = vst[j];
  }

  const int rsw = r5 & 7;            // read-row swizzle (unchanged)

  for (int t = 0; t < 16; ++t) {
    const int kv0 = kb + t * 64;
    __syncthreads();   // (1) staged writes of tile t visible

    // issue next tile's global loads (wrap within this pair's half)
    const size_t kvn = (size_t)(((t + 1) & 15) * 64);
#pragma unroll
    for (int j = 0; j < 4; ++j) {
      kst[j] = *(const bf16x8*)(Kp + (size_t)(kvn + 8 * j) * HD);
      vst[j] = *(const bf16x8*)(Vp + (size_t)(8 * j) * SEQ + kvn);
    }

    // S^T = K * Q^T
    f32x16 st0 = (f32x16){0.f};
    f32x16 st1 = (f32x16){0.f};
    __builtin_amdgcn_s_setprio(1);
#pragma unroll
    for (int j = 0; j < 4; ++j) {
      const int co = ((2 * j + hi) ^ rsw) * 8;
      bf16x8 ka0 = *(const bf16x8*)&KA[pair][r5][co];
      bf16x8 ka1 = *(const bf16x8*)&KA[pair][32 + r5][co];
      st0 = __builtin_amdgcn_mfma_f32_32x32x16_bf16(ka0, qf[j], st0, 0, 0, 0);
      st1 = __builtin_amdgcn_mfma_f32_32x32x16_bf16(ka1, qf[j], st1, 0, 0, 0);
    }
    __builtin_amdgcn_s_setprio(0);

    // fixed-max softmax
    float p[2][16];
#pragma unroll
    for (int t2 = 0; t2 < 4; ++t2) {
      f32x4 mv0 = *(const f32x4*)&mb2[kv0 + 8 * t2 + 4 * hi];
      f32x4 mv1 = *(const f32x4*)&mb2[kv0 + 32 + 8 * t2 + 4 * hi];
#pragma unroll
      for (int e = 0; e < 4; ++e) {
        p[0][4 * t2 + e] = fexp2(st0[4 * t2 + e] * C1 + mv0[e]);
        p[1][4 * t2 + e] = fexp2(st1[4 * t2 + e] * C1 + mv1[e]);
      }
    }

    // pack P -> bf16 words; in-register B-frag assembly via permlane32_swap
    unsigned int wq[2][4][2];
#pragma unroll
    for (int s2 = 0; s2 < 2; ++s2)
#pragma unroll
      for (int t2 = 0; t2 < 4; ++t2) {
        asm("v_cvt_pk_bf16_f32 %0, %1, %2"
            : "=v"(wq[s2][t2][0]) : "v"(p[s2][4 * t2 + 0]), "v"(p[s2][4 * t2 + 1]));
        asm("v_cvt_pk_bf16_f32 %0, %1, %2"
            : "=v"(wq[s2][t2][1]) : "v"(p[s2][4 * t2 + 2]), "v"(p[s2][4 * t2 + 3]));
      }

    bf16x8 pf[4];
#pragma unroll
    for (int s2 = 0; s2 < 2; ++s2)
#pragma unroll
      for (int jl = 0; jl < 2; ++jl) {
        unsigned int a0 = wq[s2][2 * jl][0], b0 = wq[s2][2 * jl + 1][0];
        unsigned int a1 = wq[s2][2 * jl][1], b1 = wq[s2][2 * jl + 1][1];
        asm("v_permlane32_swap_b32 %0, %1" : "+v"(a0), "+v"(b0));
        asm("v_permlane32_swap_b32 %0, %1" : "+v"(a1), "+v"(b1));
        uint4 fw; fw.x = a0; fw.y = a1; fw.z = b0; fw.w = b1;
        pf[2 * s2 + jl] = __builtin_bit_cast(bf16x8, fw);
      }

    // per-lane sum tree (cross-half shfl deferred)
    float sm[8];
#pragma unroll
    for (int i = 0; i < 8; ++i)
      sm[i] = (p[0][2 * i] + p[0][2 * i + 1]) + (p[1][2 * i] + p[1][2 * i + 1]);
    lsum += ((sm[0] + sm[1]) + (sm[2] + sm[3])) + ((sm[4] + sm[5]) + (sm[6] + sm[7]));

    // O^T += V^T * P^T
    __builtin_amdgcn_s_setprio(1);
#pragma unroll
    for (int j = 0; j < 4; ++j) {
      const int co = ((2 * j + hi) ^ rsw) * 8;
      bf16x8 va0 = *(const bf16x8*)&VA[pair][r5][co];
      bf16x8 va1 = *(const bf16x8*)&VA[pair][32 + r5][co];
      o0 = __builtin_amdgcn_mfma_f32_32x32x16_bf16(va0, pf[j], o0, 0, 0, 0);
      o1 = __builtin_amdgcn_mfma_f32_32x32x16_bf16(va1, pf[j], o1, 0, 0, 0);
    }
    __builtin_amdgcn_s_setprio(0);

    __syncthreads();   // (2) all reads of tile t done -> safe to overwrite
#pragma unroll
    for (int j = 0; j < 4; ++j) {
      *(bf16x8*)&KA[pair][rbase + 8 * j][ssw2 * 8] = kst[j];
      *(bf16x8*)&VA[pair][rbase + 8 * j][ssw2 * 8] = vst[j];
    }
  }

  // deferred cross-half reduce
  const float l_run = lsum + __shfl_xor(lsum, 32, 64);

  // ---- cross-pair merge: waves 2,3 publish (l,O); waves 0,1 combine ----
  __syncthreads();
  float* Os = (float*)&KA[0][0][0];   // [2][32][64] f32 = 16384 B, fits KA

  if (w >= 2) {
    const int wv = w - 2;
    float* Or = Os + (size_t)(wv * 32 + r5) * 64;
#pragma unroll
    for (int t2 = 0; t2 < 4; ++t2) {
      f32x4 v0, v1;
#pragma unroll
      for (int e = 0; e < 4; ++e) { v0[e] = o0[4 * t2 + e]; v1[e] = o1[4 * t2 + e]; }
      *(f32x4*)&Or[8 * t2 + 4 * hi]      = v0;
      *(f32x4*)&Or[32 + 8 * t2 + 4 * hi] = v1;
    }
    if (hi == 0) ML[wv * 32 + r5] = l_run;
  }
  __syncthreads();
  if (w < 2) {
    const float lo  = ML[w * 32 + r5];
    const float inv = 1.f / (l_run + lo);
    const float* Or = Os + (size_t)(w * 32 + r5) * 64;
    float* ob = out + (size_t)(b * SEQ + q0 + r5) * HID + hh * HD;
#pragma unroll
    for (int t2 = 0; t2 < 4; ++t2) {
      f32x4 po = *(const f32x4*)&Or[8 * t2 + 4 * hi];
      f32x4 p1 = *(const f32x4*)&Or[32 + 8 * t2 + 4 * hi];
      f32x4 v0, v1;
#pragma unroll
      for (int e = 0; e < 4; ++e) {
        v0[e] = (o0[4 * t2 + e] + po[e]) * inv;
        v1[e] = (o1[4 * t2 + e] + p1[e]) * inv;
      }
      *(f32x4*)&ob[8 * t2 + 4 * hi]      = v0;
      *(f32x4*)&ob[32 + 8 * t2 + 4 * hi] = v1;
    }
  }
}

// ---------------------------------------------------------------------------
extern "C" void kernel_launch(void* const* d_in, const int* in_sizes, int n_in,
                              void* d_out, int out_size, void* d_ws, size_t ws_size,
                              hipStream_t stream) {
  const float* X    = (const float*)d_in[0];
  const float* mask = (const float*)d_in[1];
  const float* Wq   = (const float*)d_in[2];
  const float* bq   = (const float*)d_in[3];
  const float* Wk   = (const float*)d_in[4];
  const float* bk   = (const float*)d_in[5];
  const float* Wv   = (const float*)d_in[6];
  const float* bv   = (const float*)d_in[7];
  float* out = (float*)d_out;

  short* Qb = (short*)d_ws;
  short* Kb = Qb + PH;
  short* Vt = Kb + PH;                 // V stored transposed [bh][d][s]
  short* Xb = Vt + PH;
  short* Wt = Xb + XEL;
  float* mask2 = (float*)(Wt + (size_t)3 * HID * HID);

  prep<<<dim3(1201), 256, 0, stream>>>(X, Wq, Wk, Wv, mask, Xb, Wt, mask2);
  qkv_gemm<<<dim3(768), 256, 0, stream>>>(Xb, Wt, bq, bk, bv, Qb, Kb, Vt);
  attn_fwd<<<dim3(768), 256, 0, stream>>>(Qb, Kb, Vt, mask2, out);
}